// Round 1
// baseline (1095.949 us; speedup 1.0000x reference)
//
#include <hip/hip_runtime.h>

#define NEG 0.01f
__device__ __forceinline__ float lrelu(float v){ return v >= 0.f ? v : NEG * v; }

typedef float v2f __attribute__((ext_vector_type(2)));
typedef short bf16x8 __attribute__((ext_vector_type(8)));   // 8 bf16 = 4 VGPRs
typedef float f32x4 __attribute__((ext_vector_type(4)));
typedef unsigned short u16;

__device__ __forceinline__ u16 f2bf(float f) {   // RNE f32 -> bf16 (finite inputs)
  unsigned u = __float_as_uint(f);
  return (u16)((u + 0x7FFFu + ((u >> 16) & 1u)) >> 16);
}

__device__ __forceinline__ float fma4(float4 wv, float4 hv, float acc) {
  return fmaf(wv.x, hv.x, fmaf(wv.y, hv.y, fmaf(wv.z, hv.z, fmaf(wv.w, hv.w, acc))));
}

// ---- LDS plan: single arena S[8192] (32768 B) ----
// Phase A (0-4a): XS@0(121, dies stage-1) | SB@0(2916, born 2a) | H2@2916(81x64)
// Phase B (4b-5): H4@0 = bf16 [81 px][72 ic-pad] (2916 dw); stage-5 = MFMA from
//                 H4 + global wb2; epilogue writes C2S@6272(32x56=1792) directly
//                 (C2S region = dead tail of H2; H2 died at stage-4 sync).
// Phase C (6+):   P6@0(1600) C3S@3392(200) D1P@3600(256) D1@3856 D2@3920
//                 D3@3952 D4@3968
// RULES:
//  (R2)  no runtime-bound loop may index a register array — full unroll +
//        per-iteration predicate only (violation = 810 MB scratch traffic).
//  (R5)  keep __launch_bounds__(256,3); do NOT force VGPR cap (spill risk).
//  (R8)  fuse T/P/G in one H2 pass; carry G in regs across softmax barrier.
//  (R9)  dense head in wave 0 only (s_waitcnt+wave_barrier ordering).
//  (R10) 32768 B arena = 5-blocks/CU LDS cliff; VGPR must stay <=64 for 20 waves.
//  (R13) stage-2a packs theta+phi via v2f fma (v_pk_fma_f32).
//  (R14) stage-5 = bf16 MFMA 16x16x32 implicit GEMM. A = H4[px][ic] (lane:
//        m=l&15, k=8*(l>>4)+i contiguous ic); B = wb2[tap][oc][ic] (col=l&15,
//        same k); C/D: row=(l>>4)*4+reg, col=l&15 (m89-verified). fp32 accum;
//        wave m-tile = wid*16; rows m>=49 read stale-but-finite arena bytes and
//        are discarded by the px<49 predicate (row-independent MFMA).
#define XS   0
#define SB   0
#define H2   2916
#define H4   0
#define C2S  6272
#define P6   0
#define C3S  3392
#define D1P  3600
#define D1   3856
#define D2   3920
#define D3   3952
#define D4   3968

// repack: w2 [oc32][ic64][9] -> wb2 bf16 [tap9][oc32][ic64] (18432 u16 = 9216 dw)
//         w3 [oc8][ic32][9]  -> pw3 fp32 [ic32][oc8][12] (pad3) at dw offset 9216
__global__ void repack_w23(const float* __restrict__ w2, const float* __restrict__ w3,
                           float* __restrict__ pw) {
  int idx = blockIdx.x * 256 + threadIdx.x;
  u16* wb2 = (u16*)pw;
  for (int i = idx; i < 9 * 32 * 64 + 32 * 8 * 12; i += gridDim.x * 256) {
    if (i < 9 * 32 * 64) {
      int ic = i & 63, oc = (i >> 6) & 31, tap = i >> 11;
      wb2[i] = f2bf(w2[(oc * 64 + ic) * 9 + tap]);
    } else {
      int j = i - 9 * 32 * 64;
      int s = j % 12, rest = j / 12, oc = rest & 7, ic = rest >> 3;
      pw[9216 + j] = (s < 9) ? w3[(oc * 32 + ic) * 9 + s] : 0.f;
    }
  }
}

__global__ __launch_bounds__(256, 3) void braggnn_fused(
    const float* __restrict__ x,
    const float* __restrict__ w1, const float* __restrict__ b1,
    const float* __restrict__ wt, const float* __restrict__ bt,
    const float* __restrict__ wp, const float* __restrict__ bp,
    const float* __restrict__ wg, const float* __restrict__ bg,
    const float* __restrict__ wo, const float* __restrict__ bo,
    const u16* __restrict__ wb2, const float* __restrict__ pw3,
    const float* __restrict__ b2,
    const float* __restrict__ b3,
    const float* __restrict__ dw1, const float* __restrict__ db1,
    const float* __restrict__ dw2, const float* __restrict__ db2,
    const float* __restrict__ dw3, const float* __restrict__ db3,
    const float* __restrict__ dw4, const float* __restrict__ db4,
    const float* __restrict__ dw5, const float* __restrict__ db5,
    float* __restrict__ out)
{
  const int b = blockIdx.x;
  const int t = threadIdx.x;

  __shared__ __align__(16) float S[8192];   // 32768 B

  // ---- stage 0: load 11x11 patch ----
  if (t < 121) S[XS + t] = x[(size_t)b * 121 + t];
  __syncthreads();

  // ---- stage 1: conv1 1->64 3x3 -> H2[px][oc] ch-major stride 64 (no act) ----
  {
    const int oc = t & 63, pg = t >> 6;
    float wreg[9];
#pragma unroll
    for (int i = 0; i < 9; i++) wreg[i] = w1[oc * 9 + i];
    const float bv = b1[oc];
    for (int px = pg; px < 81; px += 4) {
      const int y = px / 9, xx = px - y * 9;
      const float* xr = &S[XS + y * 11 + xx];
      float a = bv;
#pragma unroll
      for (int ky = 0; ky < 3; ky++)
#pragma unroll
        for (int kx = 0; kx < 3; kx++)
          a = fmaf(xr[ky * 11 + kx], wreg[ky * 3 + kx], a);
      S[H2 + px * 64 + oc] = a;
    }
  }
  __syncthreads();

  // ---- stage 2 pass A (R13): fused theta/phi packed + g, ONE H2 read ----
  float gReg[10];
  float g80 = 0.f;
  {
    const int oc = t & 31, pxb = t >> 5;
    const float4* wt4 = (const float4*)wt;
    const float4* wp4 = (const float4*)wp;
    const float4* wg4 = (const float4*)wg;
    v2f aTP[10];
#pragma unroll
    for (int i = 0; i < 10; i++) aTP[i] = (v2f){0.f, 0.f};
    float aG[10] = {0,0,0,0,0,0,0,0,0,0};
#pragma unroll 2
    for (int k4 = 0; k4 < 16; k4++) {
      const float4 wT = wt4[oc * 16 + k4];
      const float4 wP = wp4[oc * 16 + k4];
      const float4 wG = wg4[oc * 16 + k4];
      const v2f wtp0 = {wT.x, wP.x}, wtp1 = {wT.y, wP.y};
      const v2f wtp2 = {wT.z, wP.z}, wtp3 = {wT.w, wP.w};
#pragma unroll
      for (int i = 0; i < 10; i++) {
        const float4 hv = *(const float4*)&S[H2 + (pxb + 8 * i) * 64 + k4 * 4];
        aTP[i] = __builtin_elementwise_fma(wtp0, (v2f){hv.x, hv.x}, aTP[i]);
        aTP[i] = __builtin_elementwise_fma(wtp1, (v2f){hv.y, hv.y}, aTP[i]);
        aTP[i] = __builtin_elementwise_fma(wtp2, (v2f){hv.z, hv.z}, aTP[i]);
        aTP[i] = __builtin_elementwise_fma(wtp3, (v2f){hv.w, hv.w}, aTP[i]);
        aG[i] = fma4(wG, hv, aG[i]);
      }
    }
    const float bT = bt[oc], bP = bp[oc], bG = bg[oc];
#pragma unroll
    for (int i = 0; i < 10; i++) {
      S[SB + (pxb + 8 * i) * 36 + oc] = (aTP[i].x + bT) * (aTP[i].y + bP);
      gReg[i] = aG[i] + bG;
    }
    if (t < 32) {          // px = 80 leftover: oc = t
      float aT8 = 0.f, aP8 = 0.f, aG8 = 0.f;
#pragma unroll 2
      for (int k4 = 0; k4 < 16; k4++) {
        const float4 hv = *(const float4*)&S[H2 + 80 * 64 + k4 * 4];
        aT8 = fma4(wt4[t * 16 + k4], hv, aT8);
        aP8 = fma4(wp4[t * 16 + k4], hv, aP8);
        aG8 = fma4(wg4[t * 16 + k4], hv, aG8);
      }
      S[SB + 80 * 36 + t] = (aT8 + bt[t]) * (aP8 + bp[t]);
      g80 = aG8 + bg[t];
    }
  }
  __syncthreads();

  // ---- stage 2 pass B: softmax over W (9) in place on SB ----
  {
    auto sm = [&](int r) {
      const int oc = r & 31, y = r >> 5;
      const int base = SB + y * 9 * 36 + oc;
      float v[9]; float m = -1e30f;
#pragma unroll
      for (int k = 0; k < 9; k++) { v[k] = S[base + k * 36]; m = fmaxf(m, v[k]); }
      float s = 0.f;
#pragma unroll
      for (int k = 0; k < 9; k++) { v[k] = __expf(v[k] - m); s += v[k]; }
      const float inv = 1.f / s;
#pragma unroll
      for (int k = 0; k < 9; k++) S[base + k * 36] = v[k] * inv;
    };
    sm(t);
    if (t < 32) sm(256 + t);
  }
  __syncthreads();

  // ---- stage 2 pass C: SB = attn * G (G from registers, in place) ----
  {
    const int oc = t & 31, pxb = t >> 5;
#pragma unroll
    for (int i = 0; i < 10; i++) {
      const int idx = SB + (pxb + 8 * i) * 36 + oc;
      S[idx] = gReg[i] * S[idx];
    }
    if (t < 32) {
      const int idx = SB + 80 * 36 + t;
      S[idx] = g80 * S[idx];
    }
  }
  __syncthreads();

  // ---- stage 4: wo 1x1 (32->64) + residual + lrelu -> H4 bf16 [px][72] ----
  {
    const int ocq = t >> 4, q = t & 15;
    const int oc0 = ocq * 4;
    int pxs[6];
#pragma unroll
    for (int j = 0; j < 6; j++) { int p = q + 16 * j; pxs[j] = (p > 80) ? 80 : p; }
    float a0[6] = {0,0,0,0,0,0}, a1[6] = {0,0,0,0,0,0};
    float a2[6] = {0,0,0,0,0,0}, a3[6] = {0,0,0,0,0,0};
    const float4* wo4 = (const float4*)wo;
#pragma unroll 4
    for (int k4 = 0; k4 < 8; k4++) {
      const float4 u0 = wo4[(oc0 + 0) * 8 + k4];
      const float4 u1 = wo4[(oc0 + 1) * 8 + k4];
      const float4 u2 = wo4[(oc0 + 2) * 8 + k4];
      const float4 u3 = wo4[(oc0 + 3) * 8 + k4];
#pragma unroll
      for (int j = 0; j < 6; j++) {
        const float4 gv = *(const float4*)&S[SB + pxs[j] * 36 + k4 * 4];
        a0[j] = fma4(u0, gv, a0[j]); a1[j] = fma4(u1, gv, a1[j]);
        a2[j] = fma4(u2, gv, a2[j]); a3[j] = fma4(u3, gv, a3[j]);
      }
    }
    // residual pre-read (H2/SB die at the sync; H4 aliases them)
    float4 hres[6];
#pragma unroll
    for (int j = 0; j < 6; j++)
      hres[j] = *(const float4*)&S[H2 + pxs[j] * 64 + oc0];
    __syncthreads();
    const float bo0 = bo[oc0], bo1 = bo[oc0 + 1], bo2 = bo[oc0 + 2], bo3 = bo[oc0 + 3];
#pragma unroll
    for (int j = 0; j < 6; j++) {
      if (q + 16 * j <= 80) {   // unique-write predicate, compile-time unrolled
        const int px = pxs[j];
        const float v0 = lrelu(hres[j].x + a0[j] + bo0);
        const float v1 = lrelu(hres[j].y + a1[j] + bo1);
        const float v2 = lrelu(hres[j].z + a2[j] + bo2);
        const float v3 = lrelu(hres[j].w + a3[j] + bo3);
        const int hb = H4 + px * 36 + (oc0 >> 1);     // dword index, 72-bf16 row
        S[hb]     = __uint_as_float((unsigned)f2bf(v0) | ((unsigned)f2bf(v1) << 16));
        S[hb + 1] = __uint_as_float((unsigned)f2bf(v2) | ((unsigned)f2bf(v3) << 16));
      }
    }
  }
  __syncthreads();

  // ---- stage 5 (R14): conv2 64->32 3x3 as bf16 MFMA 16x16x32 ----
  {
    const int lane = t & 63, wid = t >> 6;
    const int m = lane & 15, kg = lane >> 4;      // A row, k-group
    const int opx = wid * 16 + m;                 // output px this lane feeds
    const int oy = opx / 7, ox = opx - oy * 7;
    const char* Sb = (const char*)S;
    int aoff = (oy * 9 + ox) * 144 + kg * 16;     // bytes into H4
    const u16* wbl = wb2 + (lane & 15) * 64 + kg * 8;
    f32x4 acc0 = {0.f, 0.f, 0.f, 0.f}, acc1 = {0.f, 0.f, 0.f, 0.f};
#pragma unroll 1
    for (int ky = 0; ky < 3; ky++) {
#pragma unroll
      for (int kx = 0; kx < 3; kx++) {
#pragma unroll
        for (int ks = 0; ks < 2; ks++) {
          const bf16x8 av = *(const bf16x8*)(Sb + (aoff + kx * 144 + ks * 64));
          const bf16x8 b0v = *(const bf16x8*)(wbl + kx * 2048 + ks * 32);
          const bf16x8 b1v = *(const bf16x8*)(wbl + kx * 2048 + ks * 32 + 1024);
          acc0 = __builtin_amdgcn_mfma_f32_16x16x32_bf16(av, b0v, acc0, 0, 0, 0);
          acc1 = __builtin_amdgcn_mfma_f32_16x16x32_bf16(av, b1v, acc1, 0, 0, 0);
        }
      }
      aoff += 9 * 144;        // next ky input row
      wbl  += 3 * 2048;       // next ky tap group
    }
    // epilogue: bias + lrelu -> C2S [32 oc][7 y][8 x] (fp32). No barrier needed:
    // C2S region (dead H2 tail) has no readers since the stage-4 sync.
#pragma unroll
    for (int nt = 0; nt < 2; nt++) {
      const f32x4 accv = nt ? acc1 : acc0;
      const int oc = nt * 16 + (lane & 15);
      const float bv = b2[oc];
#pragma unroll
      for (int r = 0; r < 4; r++) {
        const int px = wid * 16 + kg * 4 + r;     // C row = (lane>>4)*4 + reg
        if (px < 49) {
          const int y = px / 7, xx = px - y * 7;
          S[C2S + oc * 56 + y * 8 + xx] = lrelu(accv[r] + bv);
        }
      }
    }
  }
  __syncthreads();

  // ---- stage 6: conv3 32->8 3x3, K split in 8 groups of 4 ic, pw3 f4 loads ----
  {
    const int px = t & 31, ic8 = t >> 5;
    if (px < 25) {
      const int y = px / 5, xx = px - y * 5;
      float p[8] = {0,0,0,0,0,0,0,0};
      const float4* pw34 = (const float4*)pw3;
#pragma unroll
      for (int i = 0; i < 4; i++) {
        const int icg = ic8 * 4 + i;
        float rr[9];
#pragma unroll
        for (int ky = 0; ky < 3; ky++) {
          const int base = C2S + icg * 56 + (y + ky) * 8 + xx;
          rr[ky * 3 + 0] = S[base];
          rr[ky * 3 + 1] = S[base + 1];
          rr[ky * 3 + 2] = S[base + 2];
        }
#pragma unroll
        for (int oc = 0; oc < 8; oc++) {
          const float4 f0 = pw34[(icg * 8 + oc) * 3 + 0];
          const float4 f1 = pw34[(icg * 8 + oc) * 3 + 1];
          const float4 f2 = pw34[(icg * 8 + oc) * 3 + 2];
          p[oc] = fmaf(rr[0], f0.x, fmaf(rr[1], f0.y, fmaf(rr[2], f0.z,
                  fmaf(rr[3], f0.w, fmaf(rr[4], f1.x, fmaf(rr[5], f1.y,
                  fmaf(rr[6], f1.z, fmaf(rr[7], f1.w, fmaf(rr[8], f2.x, p[oc])))))))));
        }
      }
      float* wpp = &S[P6 + px * 64 + ic8 * 8];
#pragma unroll
      for (int oc = 0; oc < 8; oc++) wpp[oc] = p[oc];
    }
  }
  __syncthreads();
  if (t < 200) {
    const int oc = t & 7, px = t >> 3;
    float s = b3[oc];
    const float* rp = &S[P6 + px * 64 + oc];
#pragma unroll
    for (int g = 0; g < 8; g++) s += rp[g * 8];
    S[C3S + oc * 25 + px] = lrelu(s);
  }
  __syncthreads();

  // ---- stage 7: dense 200->64 partials, 4 chunks (56/56/56/32), float4 ----
  {
    const int o = t & 63, chunk = t >> 6;
    const int start = chunk * 56;
    const int cnt = (chunk == 3) ? 8 : 14;
    const float4* wr4 = (const float4*)&dw1[o * 200 + start];
    const float4* cr4 = (const float4*)&S[C3S + start];
    float acc = 0.f;
    for (int i = 0; i < cnt; i++) {   // runtime bound OK: memory only
      const float4 wv = wr4[i], cv = cr4[i];
      acc += wv.x * cv.x + wv.y * cv.y + wv.z * cv.z + wv.w * cv.w;
    }
    S[D1P + chunk * 64 + o] = acc;
  }
  __syncthreads();

  // ---- dense head: wave 0 only, no workgroup barriers (waves 1-3 retire) ----
  if (t < 64) {
    S[D1 + t] = lrelu(S[D1P + t] + S[D1P + 64 + t] + S[D1P + 128 + t] +
                      S[D1P + 192 + t] + db1[t]);
    __builtin_amdgcn_s_waitcnt(0); __builtin_amdgcn_wave_barrier();
    if (t < 32) {
      float acc = db2[t];
      const float4* wr = (const float4*)&dw2[t * 64];
      const float4* dr = (const float4*)&S[D1];
#pragma unroll
      for (int i = 0; i < 16; i++) acc = fma4(wr[i], dr[i], acc);
      S[D2 + t] = lrelu(acc);
    }
    __builtin_amdgcn_s_waitcnt(0); __builtin_amdgcn_wave_barrier();
    if (t < 16) {
      float acc = db3[t];
      const float4* wr = (const float4*)&dw3[t * 32];
      const float4* dr = (const float4*)&S[D2];
#pragma unroll
      for (int i = 0; i < 8; i++) acc = fma4(wr[i], dr[i], acc);
      S[D3 + t] = lrelu(acc);
    }
    __builtin_amdgcn_s_waitcnt(0); __builtin_amdgcn_wave_barrier();
    if (t < 8) {
      float acc = db4[t];
      const float4* wr = (const float4*)&dw4[t * 16];
      const float4* dr = (const float4*)&S[D3];
#pragma unroll
      for (int i = 0; i < 4; i++) acc = fma4(wr[i], dr[i], acc);
      S[D4 + t] = lrelu(acc);
    }
    __builtin_amdgcn_s_waitcnt(0); __builtin_amdgcn_wave_barrier();
    if (t < 2) {
      float acc = db5[t];
      const float4* wr = (const float4*)&dw5[t * 8];
      const float4* dr = (const float4*)&S[D4];
#pragma unroll
      for (int i = 0; i < 2; i++) acc = fma4(wr[i], dr[i], acc);
      out[(size_t)b * 2 + t] = acc;
    }
  }
}

extern "C" void kernel_launch(void* const* d_in, const int* in_sizes, int n_in,
                              void* d_out, int out_size, void* d_ws, size_t ws_size,
                              hipStream_t stream) {
  const float* x   = (const float*)d_in[0];
  const float* w1  = (const float*)d_in[1];
  const float* b1  = (const float*)d_in[2];
  const float* wt  = (const float*)d_in[3];
  const float* bt  = (const float*)d_in[4];
  const float* wp  = (const float*)d_in[5];
  const float* bp  = (const float*)d_in[6];
  const float* wg  = (const float*)d_in[7];
  const float* bg  = (const float*)d_in[8];
  const float* wo  = (const float*)d_in[9];
  const float* bo  = (const float*)d_in[10];
  const float* w2  = (const float*)d_in[11];
  const float* b2  = (const float*)d_in[12];
  const float* w3  = (const float*)d_in[13];
  const float* b3  = (const float*)d_in[14];
  const float* dw1 = (const float*)d_in[15];
  const float* db1 = (const float*)d_in[16];
  const float* dw2 = (const float*)d_in[17];
  const float* db2 = (const float*)d_in[18];
  const float* dw3 = (const float*)d_in[19];
  const float* db3 = (const float*)d_in[20];
  const float* dw4 = (const float*)d_in[21];
  const float* db4 = (const float*)d_in[22];
  const float* dw5 = (const float*)d_in[23];
  const float* db5 = (const float*)d_in[24];

  float* pw = (float*)d_ws;             // wb2: 9216 dw (bf16x2), pw3: 3072 dw
  repack_w23<<<32, 256, 0, stream>>>(w2, w3, pw);
  const u16* wb2 = (const u16*)pw;
  const float* pw3 = pw + 9216;

  int B = in_sizes[0] / 121;
  braggnn_fused<<<B, 256, 0, stream>>>(
      x, w1, b1, wt, bt, wp, bp, wg, bg, wo, bo, wb2, pw3, b2, b3,
      dw1, db1, dw2, db2, dw3, db3, dw4, db4, dw5, db5,
      (float*)d_out);
}

// Round 2
// 1094.827 us; speedup vs baseline: 1.0010x; 1.0010x over previous
//
#include <hip/hip_runtime.h>

#define NEG 0.01f
__device__ __forceinline__ float lrelu(float v){ return v >= 0.f ? v : NEG * v; }

typedef float v2f __attribute__((ext_vector_type(2)));
typedef short bf16x8 __attribute__((ext_vector_type(8)));   // 8 bf16 = 4 VGPRs
typedef float f32x4 __attribute__((ext_vector_type(4)));
typedef unsigned short u16;

__device__ __forceinline__ u16 f2bf(float f) {   // RNE f32 -> bf16 (finite inputs)
  unsigned u = __float_as_uint(f);
  return (u16)((u + 0x7FFFu + ((u >> 16) & 1u)) >> 16);
}
__device__ __forceinline__ float bflo(unsigned u){ return __uint_as_float(u << 16); }
__device__ __forceinline__ float bfhi(unsigned u){ return __uint_as_float(u & 0xffff0000u); }

__device__ __forceinline__ float fma4(float4 wv, float4 hv, float acc) {
  return fmaf(wv.x, hv.x, fmaf(wv.y, hv.y, fmaf(wv.z, hv.z, fmaf(wv.w, hv.w, acc))));
}

// ---- LDS plan: single arena S[5664] (22656 B -> 7 blocks/CU) ----
// Phase A (0-4a): XS@0(121, dies st-1) | H2B@128 bf16 [81px][64ic] (32dw/row,
//                 2592 dw, dies after st-4 residual pre-read) | SB@2720 fp32
//                 [81][36] (2916 dw, dies at st-4 mid-sync). Peak 5636 dw.
// Phase B (4b-5): H4@0 bf16 [81px][80 ic-pad] (40dw/row, 3240 dw; clobbers
//                 XS+H2B+SB[0..520]); st-5 MFMA from H4 + global wb2; epilogue
//                 writes C2S@3240 (32x56=1792, dead SB tail). st-5 A-reads for
//                 m>=49 touch rows<=101 (<=dw 4056, in-arena garbage, discarded).
// Phase C (6+):   P6@0(1600) C3S@1600(200) D1P@1800(256) D1@2056 D2@2120
//                 D3@2152 D4@2168  [dead H4; C2S@3240 read by stage 6]
// RULES:
//  (R2)  no runtime-bound loop may index a register array — full unroll +
//        per-iteration predicate only (violation = 810 MB scratch traffic).
//  (R5)  keep __launch_bounds__(256,3); do NOT force VGPR cap (spill risk).
//  (R8)  fuse T/P/G in one H2B pass; carry G in regs across softmax barrier.
//  (R9)  dense head in wave 0 only (s_waitcnt+wave_barrier ordering).
//  (R10) occupancy is THE lever (r1: -60% VALU work = 0 time delta). Arena
//        22656 B -> 7 blocks/CU iff VGPR<=72. Do not grow either.
//  (R13) stage-2a packs theta+phi via v2f fma (v_pk_fma_f32).
//  (R14) stage-5 = bf16 MFMA 16x16x32. A: m=l&15, k=8*(l>>4)+i; B from global
//        wb2 [tap][oc][ic]; C/D row=(l>>4)*4+reg, col=l&15. Rows m>=49 discarded.
//  (R15) H2 lives as bf16 from birth (stage-1 RNE pack): halves arena + 2a
//        reads; residual rounds ONCE. H4 row stride 40 dw: (8*(m%4)+4kg)%32
//        start-set covers each bank-group exactly 2x = 8-cy b128 optimum.
#define XS   0
#define H2B  128
#define SB   2720
#define H4   0
#define C2S  3240
#define P6   0
#define C3S  1600
#define D1P  1800
#define D1   2056
#define D2   2120
#define D3   2152
#define D4   2168

// repack: w2 [oc32][ic64][9] -> wb2 bf16 [tap9][oc32][ic64] (18432 u16 = 9216 dw)
//         w3 [oc8][ic32][9]  -> pw3 fp32 [ic32][oc8][12] (pad3) at dw offset 9216
__global__ void repack_w23(const float* __restrict__ w2, const float* __restrict__ w3,
                           float* __restrict__ pw) {
  int idx = blockIdx.x * 256 + threadIdx.x;
  u16* wb2 = (u16*)pw;
  for (int i = idx; i < 9 * 32 * 64 + 32 * 8 * 12; i += gridDim.x * 256) {
    if (i < 9 * 32 * 64) {
      int ic = i & 63, oc = (i >> 6) & 31, tap = i >> 11;
      wb2[i] = f2bf(w2[(oc * 64 + ic) * 9 + tap]);
    } else {
      int j = i - 9 * 32 * 64;
      int s = j % 12, rest = j / 12, oc = rest & 7, ic = rest >> 3;
      pw[9216 + j] = (s < 9) ? w3[(oc * 32 + ic) * 9 + s] : 0.f;
    }
  }
}

__global__ __launch_bounds__(256, 3) void braggnn_fused(
    const float* __restrict__ x,
    const float* __restrict__ w1, const float* __restrict__ b1,
    const float* __restrict__ wt, const float* __restrict__ bt,
    const float* __restrict__ wp, const float* __restrict__ bp,
    const float* __restrict__ wg, const float* __restrict__ bg,
    const float* __restrict__ wo, const float* __restrict__ bo,
    const u16* __restrict__ wb2, const float* __restrict__ pw3,
    const float* __restrict__ b2,
    const float* __restrict__ b3,
    const float* __restrict__ dw1, const float* __restrict__ db1,
    const float* __restrict__ dw2, const float* __restrict__ db2,
    const float* __restrict__ dw3, const float* __restrict__ db3,
    const float* __restrict__ dw4, const float* __restrict__ db4,
    const float* __restrict__ dw5, const float* __restrict__ db5,
    float* __restrict__ out)
{
  const int b = blockIdx.x;
  const int t = threadIdx.x;

  __shared__ __align__(16) float S[5664];   // 22656 B

  // ---- stage 0: load 11x11 patch ----
  if (t < 121) S[XS + t] = x[(size_t)b * 121 + t];
  __syncthreads();

  // ---- stage 1: conv1 1->64 3x3, oc-PAIRED -> H2B bf16 [px][64] (R15) ----
  {
    const int ocp = t & 31, pg = t >> 5;       // oc = 2*ocp, 2*ocp+1; pg 0..7
    float wreg[18];
#pragma unroll
    for (int i = 0; i < 18; i++) wreg[i] = w1[ocp * 18 + i];
    const float bv0 = b1[2 * ocp], bv1 = b1[2 * ocp + 1];
    for (int px = pg; px < 81; px += 8) {
      const int y = px / 9, xx = px - y * 9;
      const float* xr = &S[XS + y * 11 + xx];
      float a0 = bv0, a1 = bv1;
#pragma unroll
      for (int ky = 0; ky < 3; ky++)
#pragma unroll
        for (int kx = 0; kx < 3; kx++) {
          const float v = xr[ky * 11 + kx];
          a0 = fmaf(v, wreg[ky * 3 + kx], a0);
          a1 = fmaf(v, wreg[9 + ky * 3 + kx], a1);
        }
      ((unsigned*)S)[H2B + px * 32 + ocp] =
          (unsigned)f2bf(a0) | ((unsigned)f2bf(a1) << 16);
    }
  }
  __syncthreads();

  // ---- stage 2 pass A (R13): fused theta/phi packed + g, bf16 H2B reads ----
  float gReg[10];
  float g80 = 0.f;
  {
    const int oc = t & 31, pxb = t >> 5;
    const float4* wt4 = (const float4*)wt;
    const float4* wp4 = (const float4*)wp;
    const float4* wg4 = (const float4*)wg;
    const unsigned* H2u = (const unsigned*)S + H2B;
    v2f aTP[10];
#pragma unroll
    for (int i = 0; i < 10; i++) aTP[i] = (v2f){0.f, 0.f};
    float aG[10] = {0,0,0,0,0,0,0,0,0,0};
#pragma unroll 1
    for (int k8 = 0; k8 < 8; k8++) {
      const float4 wT0 = wt4[oc * 16 + 2 * k8], wT1 = wt4[oc * 16 + 2 * k8 + 1];
      const float4 wP0 = wp4[oc * 16 + 2 * k8], wP1 = wp4[oc * 16 + 2 * k8 + 1];
      const float4 wG0 = wg4[oc * 16 + 2 * k8], wG1 = wg4[oc * 16 + 2 * k8 + 1];
      const v2f p0 = {wT0.x, wP0.x}, p1 = {wT0.y, wP0.y};
      const v2f p2 = {wT0.z, wP0.z}, p3 = {wT0.w, wP0.w};
      const v2f p4 = {wT1.x, wP1.x}, p5 = {wT1.y, wP1.y};
      const v2f p6 = {wT1.z, wP1.z}, p7 = {wT1.w, wP1.w};
#pragma unroll
      for (int i = 0; i < 10; i++) {
        const uint4 hv = *(const uint4*)&H2u[(pxb + 8 * i) * 32 + k8 * 4];
        const float h0 = bflo(hv.x), h1 = bfhi(hv.x);
        const float h2 = bflo(hv.y), h3 = bfhi(hv.y);
        const float h4 = bflo(hv.z), h5 = bfhi(hv.z);
        const float h6 = bflo(hv.w), h7 = bfhi(hv.w);
        aTP[i] = __builtin_elementwise_fma(p0, (v2f){h0, h0}, aTP[i]);
        aTP[i] = __builtin_elementwise_fma(p1, (v2f){h1, h1}, aTP[i]);
        aTP[i] = __builtin_elementwise_fma(p2, (v2f){h2, h2}, aTP[i]);
        aTP[i] = __builtin_elementwise_fma(p3, (v2f){h3, h3}, aTP[i]);
        aTP[i] = __builtin_elementwise_fma(p4, (v2f){h4, h4}, aTP[i]);
        aTP[i] = __builtin_elementwise_fma(p5, (v2f){h5, h5}, aTP[i]);
        aTP[i] = __builtin_elementwise_fma(p6, (v2f){h6, h6}, aTP[i]);
        aTP[i] = __builtin_elementwise_fma(p7, (v2f){h7, h7}, aTP[i]);
        aG[i] = fmaf(h0, wG0.x, fmaf(h1, wG0.y, fmaf(h2, wG0.z, fmaf(h3, wG0.w,
                fmaf(h4, wG1.x, fmaf(h5, wG1.y, fmaf(h6, wG1.z,
                fmaf(h7, wG1.w, aG[i]))))))));
      }
    }
    const float bT = bt[oc], bP = bp[oc], bG = bg[oc];
#pragma unroll
    for (int i = 0; i < 10; i++) {
      S[SB + (pxb + 8 * i) * 36 + oc] = (aTP[i].x + bT) * (aTP[i].y + bP);
      gReg[i] = aG[i] + bG;
    }
    if (t < 32) {          // px = 80 leftover: oc = t
      float aT8 = 0.f, aP8 = 0.f, aG8 = 0.f;
#pragma unroll 1
      for (int k8 = 0; k8 < 8; k8++) {
        const uint4 hv = *(const uint4*)&H2u[80 * 32 + k8 * 4];
        const float h0 = bflo(hv.x), h1 = bfhi(hv.x);
        const float h2 = bflo(hv.y), h3 = bfhi(hv.y);
        const float h4 = bflo(hv.z), h5 = bfhi(hv.z);
        const float h6 = bflo(hv.w), h7 = bfhi(hv.w);
        const float4 a = wt4[t * 16 + 2 * k8], a2 = wt4[t * 16 + 2 * k8 + 1];
        const float4 c = wp4[t * 16 + 2 * k8], c2 = wp4[t * 16 + 2 * k8 + 1];
        const float4 e = wg4[t * 16 + 2 * k8], e2 = wg4[t * 16 + 2 * k8 + 1];
        aT8 = fmaf(h0,a.x,fmaf(h1,a.y,fmaf(h2,a.z,fmaf(h3,a.w,
              fmaf(h4,a2.x,fmaf(h5,a2.y,fmaf(h6,a2.z,fmaf(h7,a2.w,aT8))))))));
        aP8 = fmaf(h0,c.x,fmaf(h1,c.y,fmaf(h2,c.z,fmaf(h3,c.w,
              fmaf(h4,c2.x,fmaf(h5,c2.y,fmaf(h6,c2.z,fmaf(h7,c2.w,aP8))))))));
        aG8 = fmaf(h0,e.x,fmaf(h1,e.y,fmaf(h2,e.z,fmaf(h3,e.w,
              fmaf(h4,e2.x,fmaf(h5,e2.y,fmaf(h6,e2.z,fmaf(h7,e2.w,aG8))))))));
      }
      S[SB + 80 * 36 + t] = (aT8 + bt[t]) * (aP8 + bp[t]);
      g80 = aG8 + bg[t];
    }
  }
  __syncthreads();

  // ---- stage 2 pass B: softmax over W (9) in place on SB ----
  {
    auto sm = [&](int r) {
      const int oc = r & 31, y = r >> 5;
      const int base = SB + y * 9 * 36 + oc;
      float v[9]; float m = -1e30f;
#pragma unroll
      for (int k = 0; k < 9; k++) { v[k] = S[base + k * 36]; m = fmaxf(m, v[k]); }
      float s = 0.f;
#pragma unroll
      for (int k = 0; k < 9; k++) { v[k] = __expf(v[k] - m); s += v[k]; }
      const float inv = 1.f / s;
#pragma unroll
      for (int k = 0; k < 9; k++) S[base + k * 36] = v[k] * inv;
    };
    sm(t);
    if (t < 32) sm(256 + t);
  }
  __syncthreads();

  // ---- stage 2 pass C: SB = attn * G (G from registers, in place) ----
  {
    const int oc = t & 31, pxb = t >> 5;
#pragma unroll
    for (int i = 0; i < 10; i++) {
      const int idx = SB + (pxb + 8 * i) * 36 + oc;
      S[idx] = gReg[i] * S[idx];
    }
    if (t < 32) {
      const int idx = SB + 80 * 36 + t;
      S[idx] = g80 * S[idx];
    }
  }
  __syncthreads();

  // ---- stage 4: wo 1x1 (32->64) + residual + lrelu -> H4 bf16 [px][80] ----
  {
    const int ocq = t >> 4, q = t & 15;
    const int oc0 = ocq * 4;
    int pxs[6];
#pragma unroll
    for (int j = 0; j < 6; j++) { int p = q + 16 * j; pxs[j] = (p > 80) ? 80 : p; }
    float a0[6] = {0,0,0,0,0,0}, a1[6] = {0,0,0,0,0,0};
    float a2[6] = {0,0,0,0,0,0}, a3[6] = {0,0,0,0,0,0};
    const float4* wo4 = (const float4*)wo;
#pragma unroll 4
    for (int k4 = 0; k4 < 8; k4++) {
      const float4 u0 = wo4[(oc0 + 0) * 8 + k4];
      const float4 u1 = wo4[(oc0 + 1) * 8 + k4];
      const float4 u2 = wo4[(oc0 + 2) * 8 + k4];
      const float4 u3 = wo4[(oc0 + 3) * 8 + k4];
#pragma unroll
      for (int j = 0; j < 6; j++) {
        const float4 gv = *(const float4*)&S[SB + pxs[j] * 36 + k4 * 4];
        a0[j] = fma4(u0, gv, a0[j]); a1[j] = fma4(u1, gv, a1[j]);
        a2[j] = fma4(u2, gv, a2[j]); a3[j] = fma4(u3, gv, a3[j]);
      }
    }
    // residual pre-read, packed bf16 (H2B/SB die at the sync; H4 aliases them)
    uint2 hres[6];
    const unsigned* H2u = (const unsigned*)S + H2B;
#pragma unroll
    for (int j = 0; j < 6; j++)
      hres[j] = *(const uint2*)&H2u[pxs[j] * 32 + (oc0 >> 1)];
    __syncthreads();
    const float bo0 = bo[oc0], bo1 = bo[oc0 + 1], bo2 = bo[oc0 + 2], bo3 = bo[oc0 + 3];
#pragma unroll
    for (int j = 0; j < 6; j++) {
      if (q + 16 * j <= 80) {   // unique-write predicate, compile-time unrolled
        const int px = pxs[j];
        const float v0 = lrelu(bflo(hres[j].x) + a0[j] + bo0);
        const float v1 = lrelu(bfhi(hres[j].x) + a1[j] + bo1);
        const float v2 = lrelu(bflo(hres[j].y) + a2[j] + bo2);
        const float v3 = lrelu(bfhi(hres[j].y) + a3[j] + bo3);
        uint2 pk;
        pk.x = (unsigned)f2bf(v0) | ((unsigned)f2bf(v1) << 16);
        pk.y = (unsigned)f2bf(v2) | ((unsigned)f2bf(v3) << 16);
        *(uint2*)&((unsigned*)S)[H4 + px * 40 + (oc0 >> 1)] = pk;
      }
    }
  }
  __syncthreads();

  // ---- stage 5 (R14): conv2 64->32 3x3 as bf16 MFMA 16x16x32 ----
  {
    const int lane = t & 63, wid = t >> 6;
    const int m = lane & 15, kg = lane >> 4;      // A row, k-group
    const int opx = wid * 16 + m;                 // output px this lane feeds
    const int oy = opx / 7, ox = opx - oy * 7;
    const char* Sb = (const char*)S;
    int aoff = (oy * 9 + ox) * 160 + kg * 16;     // bytes into H4 (160 B/row)
    const u16* wbl = wb2 + (lane & 15) * 64 + kg * 8;
    f32x4 acc0 = {0.f, 0.f, 0.f, 0.f}, acc1 = {0.f, 0.f, 0.f, 0.f};
#pragma unroll 1
    for (int ky = 0; ky < 3; ky++) {
#pragma unroll
      for (int kx = 0; kx < 3; kx++) {
#pragma unroll
        for (int ks = 0; ks < 2; ks++) {
          const bf16x8 av = *(const bf16x8*)(Sb + (aoff + kx * 160 + ks * 64));
          const bf16x8 b0v = *(const bf16x8*)(wbl + kx * 2048 + ks * 32);
          const bf16x8 b1v = *(const bf16x8*)(wbl + kx * 2048 + ks * 32 + 1024);
          acc0 = __builtin_amdgcn_mfma_f32_16x16x32_bf16(av, b0v, acc0, 0, 0, 0);
          acc1 = __builtin_amdgcn_mfma_f32_16x16x32_bf16(av, b1v, acc1, 0, 0, 0);
        }
      }
      aoff += 9 * 160;        // next ky input row
      wbl  += 3 * 2048;       // next ky tap group
    }
    // epilogue: bias + lrelu -> C2S [32 oc][7 y][8 x] (fp32). No barrier needed:
    // C2S region (dead SB tail) has no readers since the stage-4 sync.
#pragma unroll
    for (int nt = 0; nt < 2; nt++) {
      const f32x4 accv = nt ? acc1 : acc0;
      const int oc = nt * 16 + (lane & 15);
      const float bv = b2[oc];
#pragma unroll
      for (int r = 0; r < 4; r++) {
        const int px = wid * 16 + kg * 4 + r;     // C row = (lane>>4)*4 + reg
        if (px < 49) {
          const int y = px / 7, xx = px - y * 7;
          S[C2S + oc * 56 + y * 8 + xx] = lrelu(accv[r] + bv);
        }
      }
    }
  }
  __syncthreads();

  // ---- stage 6: conv3 32->8 3x3, K split in 8 groups of 4 ic, pw3 f4 loads ----
  {
    const int px = t & 31, ic8 = t >> 5;
    if (px < 25) {
      const int y = px / 5, xx = px - y * 5;
      float p[8] = {0,0,0,0,0,0,0,0};
      const float4* pw34 = (const float4*)pw3;
#pragma unroll
      for (int i = 0; i < 4; i++) {
        const int icg = ic8 * 4 + i;
        float rr[9];
#pragma unroll
        for (int ky = 0; ky < 3; ky++) {
          const int base = C2S + icg * 56 + (y + ky) * 8 + xx;
          rr[ky * 3 + 0] = S[base];
          rr[ky * 3 + 1] = S[base + 1];
          rr[ky * 3 + 2] = S[base + 2];
        }
#pragma unroll
        for (int oc = 0; oc < 8; oc++) {
          const float4 f0 = pw34[(icg * 8 + oc) * 3 + 0];
          const float4 f1 = pw34[(icg * 8 + oc) * 3 + 1];
          const float4 f2 = pw34[(icg * 8 + oc) * 3 + 2];
          p[oc] = fmaf(rr[0], f0.x, fmaf(rr[1], f0.y, fmaf(rr[2], f0.z,
                  fmaf(rr[3], f0.w, fmaf(rr[4], f1.x, fmaf(rr[5], f1.y,
                  fmaf(rr[6], f1.z, fmaf(rr[7], f1.w, fmaf(rr[8], f2.x, p[oc])))))))));
        }
      }
      float* wpp = &S[P6 + px * 64 + ic8 * 8];
#pragma unroll
      for (int oc = 0; oc < 8; oc++) wpp[oc] = p[oc];
    }
  }
  __syncthreads();
  if (t < 200) {
    const int oc = t & 7, px = t >> 3;
    float s = b3[oc];
    const float* rp = &S[P6 + px * 64 + oc];
#pragma unroll
    for (int g = 0; g < 8; g++) s += rp[g * 8];
    S[C3S + oc * 25 + px] = lrelu(s);
  }
  __syncthreads();

  // ---- stage 7: dense 200->64 partials, 4 chunks (56/56/56/32), float4 ----
  {
    const int o = t & 63, chunk = t >> 6;
    const int start = chunk * 56;
    const int cnt = (chunk == 3) ? 8 : 14;
    const float4* wr4 = (const float4*)&dw1[o * 200 + start];
    const float4* cr4 = (const float4*)&S[C3S + start];
    float acc = 0.f;
    for (int i = 0; i < cnt; i++) {   // runtime bound OK: memory only
      const float4 wv = wr4[i], cv = cr4[i];
      acc += wv.x * cv.x + wv.y * cv.y + wv.z * cv.z + wv.w * cv.w;
    }
    S[D1P + chunk * 64 + o] = acc;
  }
  __syncthreads();

  // ---- dense head: wave 0 only, no workgroup barriers (waves 1-3 retire) ----
  if (t < 64) {
    S[D1 + t] = lrelu(S[D1P + t] + S[D1P + 64 + t] + S[D1P + 128 + t] +
                      S[D1P + 192 + t] + db1[t]);
    __builtin_amdgcn_s_waitcnt(0); __builtin_amdgcn_wave_barrier();
    if (t < 32) {
      float acc = db2[t];
      const float4* wr = (const float4*)&dw2[t * 64];
      const float4* dr = (const float4*)&S[D1];
#pragma unroll
      for (int i = 0; i < 16; i++) acc = fma4(wr[i], dr[i], acc);
      S[D2 + t] = lrelu(acc);
    }
    __builtin_amdgcn_s_waitcnt(0); __builtin_amdgcn_wave_barrier();
    if (t < 16) {
      float acc = db3[t];
      const float4* wr = (const float4*)&dw3[t * 32];
      const float4* dr = (const float4*)&S[D2];
#pragma unroll
      for (int i = 0; i < 8; i++) acc = fma4(wr[i], dr[i], acc);
      S[D3 + t] = lrelu(acc);
    }
    __builtin_amdgcn_s_waitcnt(0); __builtin_amdgcn_wave_barrier();
    if (t < 8) {
      float acc = db4[t];
      const float4* wr = (const float4*)&dw4[t * 16];
      const float4* dr = (const float4*)&S[D3];
#pragma unroll
      for (int i = 0; i < 4; i++) acc = fma4(wr[i], dr[i], acc);
      S[D4 + t] = lrelu(acc);
    }
    __builtin_amdgcn_s_waitcnt(0); __builtin_amdgcn_wave_barrier();
    if (t < 2) {
      float acc = db5[t];
      const float4* wr = (const float4*)&dw5[t * 8];
      const float4* dr = (const float4*)&S[D4];
#pragma unroll
      for (int i = 0; i < 2; i++) acc = fma4(wr[i], dr[i], acc);
      out[(size_t)b * 2 + t] = acc;
    }
  }
}

extern "C" void kernel_launch(void* const* d_in, const int* in_sizes, int n_in,
                              void* d_out, int out_size, void* d_ws, size_t ws_size,
                              hipStream_t stream) {
  const float* x   = (const float*)d_in[0];
  const float* w1  = (const float*)d_in[1];
  const float* b1  = (const float*)d_in[2];
  const float* wt  = (const float*)d_in[3];
  const float* bt  = (const float*)d_in[4];
  const float* wp  = (const float*)d_in[5];
  const float* bp  = (const float*)d_in[6];
  const float* wg  = (const float*)d_in[7];
  const float* bg  = (const float*)d_in[8];
  const float* wo  = (const float*)d_in[9];
  const float* bo  = (const float*)d_in[10];
  const float* w2  = (const float*)d_in[11];
  const float* b2  = (const float*)d_in[12];
  const float* w3  = (const float*)d_in[13];
  const float* b3  = (const float*)d_in[14];
  const float* dw1 = (const float*)d_in[15];
  const float* db1 = (const float*)d_in[16];
  const float* dw2 = (const float*)d_in[17];
  const float* db2 = (const float*)d_in[18];
  const float* dw3 = (const float*)d_in[19];
  const float* db3 = (const float*)d_in[20];
  const float* dw4 = (const float*)d_in[21];
  const float* db4 = (const float*)d_in[22];
  const float* dw5 = (const float*)d_in[23];
  const float* db5 = (const float*)d_in[24];

  float* pw = (float*)d_ws;             // wb2: 9216 dw (bf16x2), pw3: 3072 dw
  repack_w23<<<32, 256, 0, stream>>>(w2, w3, pw);
  const u16* wb2 = (const u16*)pw;
  const float* pw3 = pw + 9216;

  int B = in_sizes[0] / 121;
  braggnn_fused<<<B, 256, 0, stream>>>(
      x, w1, b1, wt, bt, wp, bp, wg, bg, wo, bo, wb2, pw3, b2, b3,
      dw1, db1, dw2, db2, dw3, db3, dw4, db4, dw5, db5,
      (float*)d_out);
}

// Round 3
// 1074.214 us; speedup vs baseline: 1.0202x; 1.0192x over previous
//
#include <hip/hip_runtime.h>

#define NEG 0.01f
__device__ __forceinline__ float lrelu(float v){ return v >= 0.f ? v : NEG * v; }

typedef float v2f __attribute__((ext_vector_type(2)));
typedef short bf16x8 __attribute__((ext_vector_type(8)));   // 8 bf16 = 4 VGPRs
typedef float f32x4 __attribute__((ext_vector_type(4)));
typedef unsigned short u16;

__device__ __forceinline__ u16 f2bf(float f) {   // RNE f32 -> bf16 (finite inputs)
  unsigned u = __float_as_uint(f);
  return (u16)((u + 0x7FFFu + ((u >> 16) & 1u)) >> 16);
}
__device__ __forceinline__ float bflo(unsigned u){ return __uint_as_float(u << 16); }
__device__ __forceinline__ float bfhi(unsigned u){ return __uint_as_float(u & 0xffff0000u); }

__device__ __forceinline__ float fma4(float4 wv, float4 hv, float acc) {
  return fmaf(wv.x, hv.x, fmaf(wv.y, hv.y, fmaf(wv.z, hv.z, fmaf(wv.w, hv.w, acc))));
}

// ---- LDS plan: single arena S[5664] (22656 B -> 7 blocks/CU) ----
// Phase A (0-4a): XS@0(121, dies st-1) | H2B@128 bf16 [81px][64ic] (32dw/row,
//                 2592 dw, dies after st-4 residual fold) | SB@2720 fp32
//                 [81][36] (2916 dw, dies at st-4 mid-sync). Peak 5636 dw.
// Phase B (4b-5): H4@0 bf16 [81px][80 ic-pad] (40dw/row, 3240 dw; clobbers
//                 XS+H2B+SB[0..520]); st-5 MFMA from H4 + global wb2; epilogue
//                 writes C2S@3240 (32x56=1792, dead SB tail). st-5 A-reads for
//                 m>=49 touch rows<=101 (<=dw 4056, in-arena garbage, discarded).
// Phase C (6+):   P6@0(1600) C3S@1600(200) D1P@1800(256) D1@2056 D2@2120
//                 D3@2152 D4@2168  [dead H4; C2S@3240 read by stage 6]
// RULES:
//  (R2)  no runtime-bound loop may index a register array — full unroll +
//        per-iteration predicate only (violation = 810 MB scratch traffic).
//  (R5-rev) launch_bounds(256,8) hard-caps VGPR=64. Old spill warning applied
//        to the VALU conv2 (49 acc regs); MFMA stage-5 needs only 8+12. If
//        VGPR_Count>64 or WRITE_SIZE grows, the cap spilled — back off.
//  (R8)  fuse T/P/G in one H2B pass; carry G in regs across softmax barrier.
//  (R9)  dense head in wave 0 only (s_waitcnt+wave_barrier ordering).
//  (R10) occupancy is THE lever (r1: -60% VALU work = 0 time delta).
//  (R13) stage-2a packs theta+phi via v2f fma (v_pk_fma_f32).
//  (R14) stage-5 = bf16 MFMA 16x16x32. A: m=l&15, k=8*(l>>4)+i; B from global
//        wb2 [tap][oc][ic]; C/D row=(l>>4)*4+reg, col=l&15. Rows m>=49 discarded.
//  (R15) H2 lives as bf16 from birth (stage-1 RNE pack); residual rounds ONCE.
//        H4 row stride 40 dw spreads stage-5 A-reads across all bank-groups.
//  (R16) HW VGPR quantum is coarse above 64 (m69: occupancy steps at 64/128/
//        256): VGPR=68 allocates 128 -> 4 waves/SIMD -> 4 blocks/CU, which is
//        why r1/r2's LDS shrink bought nothing. VGPR<=64 -> 8 waves/SIMD,
//        LDS then binds at 7 blocks/CU. Achieved occ ~ 0.7x theoretical.
//  (R17) stage-4 residual folds into wo-accumulators BEFORE the barrier
//        (a+=hres; lrelu(a+bo) — exact same fp association, 12 fewer
//        live-across-barrier VGPRs).
#define XS   0
#define H2B  128
#define SB   2720
#define H4   0
#define C2S  3240
#define P6   0
#define C3S  1600
#define D1P  1800
#define D1   2056
#define D2   2120
#define D3   2152
#define D4   2168

// repack: w2 [oc32][ic64][9] -> wb2 bf16 [tap9][oc32][ic64] (18432 u16 = 9216 dw)
//         w3 [oc8][ic32][9]  -> pw3 fp32 [ic32][oc8][12] (pad3) at dw offset 9216
__global__ void repack_w23(const float* __restrict__ w2, const float* __restrict__ w3,
                           float* __restrict__ pw) {
  int idx = blockIdx.x * 256 + threadIdx.x;
  u16* wb2 = (u16*)pw;
  for (int i = idx; i < 9 * 32 * 64 + 32 * 8 * 12; i += gridDim.x * 256) {
    if (i < 9 * 32 * 64) {
      int ic = i & 63, oc = (i >> 6) & 31, tap = i >> 11;
      wb2[i] = f2bf(w2[(oc * 64 + ic) * 9 + tap]);
    } else {
      int j = i - 9 * 32 * 64;
      int s = j % 12, rest = j / 12, oc = rest & 7, ic = rest >> 3;
      pw[9216 + j] = (s < 9) ? w3[(oc * 32 + ic) * 9 + s] : 0.f;
    }
  }
}

__global__ __launch_bounds__(256, 8) void braggnn_fused(
    const float* __restrict__ x,
    const float* __restrict__ w1, const float* __restrict__ b1,
    const float* __restrict__ wt, const float* __restrict__ bt,
    const float* __restrict__ wp, const float* __restrict__ bp,
    const float* __restrict__ wg, const float* __restrict__ bg,
    const float* __restrict__ wo, const float* __restrict__ bo,
    const u16* __restrict__ wb2, const float* __restrict__ pw3,
    const float* __restrict__ b2,
    const float* __restrict__ b3,
    const float* __restrict__ dw1, const float* __restrict__ db1,
    const float* __restrict__ dw2, const float* __restrict__ db2,
    const float* __restrict__ dw3, const float* __restrict__ db3,
    const float* __restrict__ dw4, const float* __restrict__ db4,
    const float* __restrict__ dw5, const float* __restrict__ db5,
    float* __restrict__ out)
{
  const int b = blockIdx.x;
  const int t = threadIdx.x;

  __shared__ __align__(16) float S[5664];   // 22656 B

  // ---- stage 0: load 11x11 patch ----
  if (t < 121) S[XS + t] = x[(size_t)b * 121 + t];
  __syncthreads();

  // ---- stage 1: conv1 1->64 3x3, oc-PAIRED -> H2B bf16 [px][64] (R15) ----
  {
    const int ocp = t & 31, pg = t >> 5;       // oc = 2*ocp, 2*ocp+1; pg 0..7
    float wreg[18];
#pragma unroll
    for (int i = 0; i < 18; i++) wreg[i] = w1[ocp * 18 + i];
    const float bv0 = b1[2 * ocp], bv1 = b1[2 * ocp + 1];
    for (int px = pg; px < 81; px += 8) {
      const int y = px / 9, xx = px - y * 9;
      const float* xr = &S[XS + y * 11 + xx];
      float a0 = bv0, a1 = bv1;
#pragma unroll
      for (int ky = 0; ky < 3; ky++)
#pragma unroll
        for (int kx = 0; kx < 3; kx++) {
          const float v = xr[ky * 11 + kx];
          a0 = fmaf(v, wreg[ky * 3 + kx], a0);
          a1 = fmaf(v, wreg[9 + ky * 3 + kx], a1);
        }
      ((unsigned*)S)[H2B + px * 32 + ocp] =
          (unsigned)f2bf(a0) | ((unsigned)f2bf(a1) << 16);
    }
  }
  __syncthreads();

  // ---- stage 2 pass A (R13): fused theta/phi packed + g, bf16 H2B reads ----
  float gReg[10];
  float g80 = 0.f;
  {
    const int oc = t & 31, pxb = t >> 5;
    const float4* wt4 = (const float4*)wt;
    const float4* wp4 = (const float4*)wp;
    const float4* wg4 = (const float4*)wg;
    const unsigned* H2u = (const unsigned*)S + H2B;
    v2f aTP[10];
#pragma unroll
    for (int i = 0; i < 10; i++) aTP[i] = (v2f){0.f, 0.f};
    float aG[10] = {0,0,0,0,0,0,0,0,0,0};
#pragma unroll 1
    for (int k8 = 0; k8 < 8; k8++) {
      const float4 wT0 = wt4[oc * 16 + 2 * k8];
      const float4 wP0 = wp4[oc * 16 + 2 * k8];
      const v2f p0 = {wT0.x, wP0.x}, p1 = {wT0.y, wP0.y};
      const v2f p2 = {wT0.z, wP0.z}, p3 = {wT0.w, wP0.w};
      const float4 wT1 = wt4[oc * 16 + 2 * k8 + 1];
      const float4 wP1 = wp4[oc * 16 + 2 * k8 + 1];
      const v2f p4 = {wT1.x, wP1.x}, p5 = {wT1.y, wP1.y};
      const v2f p6 = {wT1.z, wP1.z}, p7 = {wT1.w, wP1.w};
      const float4 wG0 = wg4[oc * 16 + 2 * k8];
      const float4 wG1 = wg4[oc * 16 + 2 * k8 + 1];
#pragma unroll
      for (int i = 0; i < 10; i++) {
        const uint4 hv = *(const uint4*)&H2u[(pxb + 8 * i) * 32 + k8 * 4];
        const float h0 = bflo(hv.x), h1 = bfhi(hv.x);
        const float h2 = bflo(hv.y), h3 = bfhi(hv.y);
        const float h4 = bflo(hv.z), h5 = bfhi(hv.z);
        const float h6 = bflo(hv.w), h7 = bfhi(hv.w);
        aTP[i] = __builtin_elementwise_fma(p0, (v2f){h0, h0}, aTP[i]);
        aTP[i] = __builtin_elementwise_fma(p1, (v2f){h1, h1}, aTP[i]);
        aTP[i] = __builtin_elementwise_fma(p2, (v2f){h2, h2}, aTP[i]);
        aTP[i] = __builtin_elementwise_fma(p3, (v2f){h3, h3}, aTP[i]);
        aTP[i] = __builtin_elementwise_fma(p4, (v2f){h4, h4}, aTP[i]);
        aTP[i] = __builtin_elementwise_fma(p5, (v2f){h5, h5}, aTP[i]);
        aTP[i] = __builtin_elementwise_fma(p6, (v2f){h6, h6}, aTP[i]);
        aTP[i] = __builtin_elementwise_fma(p7, (v2f){h7, h7}, aTP[i]);
        aG[i] = fmaf(h0, wG0.x, fmaf(h1, wG0.y, fmaf(h2, wG0.z, fmaf(h3, wG0.w,
                fmaf(h4, wG1.x, fmaf(h5, wG1.y, fmaf(h6, wG1.z,
                fmaf(h7, wG1.w, aG[i]))))))));
      }
    }
    const float bT = bt[oc], bP = bp[oc], bG = bg[oc];
#pragma unroll
    for (int i = 0; i < 10; i++) {
      S[SB + (pxb + 8 * i) * 36 + oc] = (aTP[i].x + bT) * (aTP[i].y + bP);
      gReg[i] = aG[i] + bG;
    }
    if (t < 32) {          // px = 80 leftover: oc = t
      float aT8 = 0.f, aP8 = 0.f, aG8 = 0.f;
#pragma unroll 1
      for (int k8 = 0; k8 < 8; k8++) {
        const uint4 hv = *(const uint4*)&H2u[80 * 32 + k8 * 4];
        const float h0 = bflo(hv.x), h1 = bfhi(hv.x);
        const float h2 = bflo(hv.y), h3 = bfhi(hv.y);
        const float h4 = bflo(hv.z), h5 = bfhi(hv.z);
        const float h6 = bflo(hv.w), h7 = bfhi(hv.w);
        const float4 a = wt4[t * 16 + 2 * k8], a2 = wt4[t * 16 + 2 * k8 + 1];
        const float4 c = wp4[t * 16 + 2 * k8], c2 = wp4[t * 16 + 2 * k8 + 1];
        const float4 e = wg4[t * 16 + 2 * k8], e2 = wg4[t * 16 + 2 * k8 + 1];
        aT8 = fmaf(h0,a.x,fmaf(h1,a.y,fmaf(h2,a.z,fmaf(h3,a.w,
              fmaf(h4,a2.x,fmaf(h5,a2.y,fmaf(h6,a2.z,fmaf(h7,a2.w,aT8))))))));
        aP8 = fmaf(h0,c.x,fmaf(h1,c.y,fmaf(h2,c.z,fmaf(h3,c.w,
              fmaf(h4,c2.x,fmaf(h5,c2.y,fmaf(h6,c2.z,fmaf(h7,c2.w,aP8))))))));
        aG8 = fmaf(h0,e.x,fmaf(h1,e.y,fmaf(h2,e.z,fmaf(h3,e.w,
              fmaf(h4,e2.x,fmaf(h5,e2.y,fmaf(h6,e2.z,fmaf(h7,e2.w,aG8))))))));
      }
      S[SB + 80 * 36 + t] = (aT8 + bt[t]) * (aP8 + bp[t]);
      g80 = aG8 + bg[t];
    }
  }
  __syncthreads();

  // ---- stage 2 pass B: softmax over W (9) in place on SB ----
  {
    auto sm = [&](int r) {
      const int oc = r & 31, y = r >> 5;
      const int base = SB + y * 9 * 36 + oc;
      float v[9]; float m = -1e30f;
#pragma unroll
      for (int k = 0; k < 9; k++) { v[k] = S[base + k * 36]; m = fmaxf(m, v[k]); }
      float s = 0.f;
#pragma unroll
      for (int k = 0; k < 9; k++) { v[k] = __expf(v[k] - m); s += v[k]; }
      const float inv = 1.f / s;
#pragma unroll
      for (int k = 0; k < 9; k++) S[base + k * 36] = v[k] * inv;
    };
    sm(t);
    if (t < 32) sm(256 + t);
  }
  __syncthreads();

  // ---- stage 2 pass C: SB = attn * G (G from registers, in place) ----
  {
    const int oc = t & 31, pxb = t >> 5;
#pragma unroll
    for (int i = 0; i < 10; i++) {
      const int idx = SB + (pxb + 8 * i) * 36 + oc;
      S[idx] = gReg[i] * S[idx];
    }
    if (t < 32) {
      const int idx = SB + 80 * 36 + t;
      S[idx] = g80 * S[idx];
    }
  }
  __syncthreads();

  // ---- stage 4: wo 1x1 (32->64) + residual + lrelu -> H4 bf16 [px][80] ----
  {
    const int ocq = t >> 4, q = t & 15;
    const int oc0 = ocq * 4;
    int pxs[6];
#pragma unroll
    for (int j = 0; j < 6; j++) { int p = q + 16 * j; pxs[j] = (p > 80) ? 80 : p; }
    float a0[6] = {0,0,0,0,0,0}, a1[6] = {0,0,0,0,0,0};
    float a2[6] = {0,0,0,0,0,0}, a3[6] = {0,0,0,0,0,0};
    const float4* wo4 = (const float4*)wo;
#pragma unroll 4
    for (int k4 = 0; k4 < 8; k4++) {
      const float4 u0 = wo4[(oc0 + 0) * 8 + k4];
      const float4 u1 = wo4[(oc0 + 1) * 8 + k4];
      const float4 u2 = wo4[(oc0 + 2) * 8 + k4];
      const float4 u3 = wo4[(oc0 + 3) * 8 + k4];
#pragma unroll
      for (int j = 0; j < 6; j++) {
        const float4 gv = *(const float4*)&S[SB + pxs[j] * 36 + k4 * 4];
        a0[j] = fma4(u0, gv, a0[j]); a1[j] = fma4(u1, gv, a1[j]);
        a2[j] = fma4(u2, gv, a2[j]); a3[j] = fma4(u3, gv, a3[j]);
      }
    }
    // (R17) fold residual into accumulators BEFORE the barrier; hres regs die
    // here instead of living across the sync. Same fp association as before.
    {
      const unsigned* H2u = (const unsigned*)S + H2B;
#pragma unroll
      for (int j = 0; j < 6; j++) {
        const uint2 h = *(const uint2*)&H2u[pxs[j] * 32 + (oc0 >> 1)];
        a0[j] += bflo(h.x); a1[j] += bfhi(h.x);
        a2[j] += bflo(h.y); a3[j] += bfhi(h.y);
      }
    }
    __syncthreads();
    const float bo0 = bo[oc0], bo1 = bo[oc0 + 1], bo2 = bo[oc0 + 2], bo3 = bo[oc0 + 3];
#pragma unroll
    for (int j = 0; j < 6; j++) {
      if (q + 16 * j <= 80) {   // unique-write predicate, compile-time unrolled
        const int px = pxs[j];
        const float v0 = lrelu(a0[j] + bo0);
        const float v1 = lrelu(a1[j] + bo1);
        const float v2 = lrelu(a2[j] + bo2);
        const float v3 = lrelu(a3[j] + bo3);
        uint2 pk;
        pk.x = (unsigned)f2bf(v0) | ((unsigned)f2bf(v1) << 16);
        pk.y = (unsigned)f2bf(v2) | ((unsigned)f2bf(v3) << 16);
        *(uint2*)&((unsigned*)S)[H4 + px * 40 + (oc0 >> 1)] = pk;
      }
    }
  }
  __syncthreads();

  // ---- stage 5 (R14): conv2 64->32 3x3 as bf16 MFMA 16x16x32 ----
  {
    const int lane = t & 63, wid = t >> 6;
    const int m = lane & 15, kg = lane >> 4;      // A row, k-group
    const int opx = wid * 16 + m;                 // output px this lane feeds
    const int oy = opx / 7, ox = opx - oy * 7;
    const char* Sb = (const char*)S;
    int aoff = (oy * 9 + ox) * 160 + kg * 16;     // bytes into H4 (160 B/row)
    const u16* wbl = wb2 + (lane & 15) * 64 + kg * 8;
    f32x4 acc0 = {0.f, 0.f, 0.f, 0.f}, acc1 = {0.f, 0.f, 0.f, 0.f};
#pragma unroll 1
    for (int ky = 0; ky < 3; ky++) {
#pragma unroll
      for (int kx = 0; kx < 3; kx++) {
#pragma unroll
        for (int ks = 0; ks < 2; ks++) {
          const bf16x8 av = *(const bf16x8*)(Sb + (aoff + kx * 160 + ks * 64));
          const bf16x8 b0v = *(const bf16x8*)(wbl + kx * 2048 + ks * 32);
          const bf16x8 b1v = *(const bf16x8*)(wbl + kx * 2048 + ks * 32 + 1024);
          acc0 = __builtin_amdgcn_mfma_f32_16x16x32_bf16(av, b0v, acc0, 0, 0, 0);
          acc1 = __builtin_amdgcn_mfma_f32_16x16x32_bf16(av, b1v, acc1, 0, 0, 0);
        }
      }
      aoff += 9 * 160;        // next ky input row
      wbl  += 3 * 2048;       // next ky tap group
    }
    // epilogue: bias + lrelu -> C2S [32 oc][7 y][8 x] (fp32). No barrier needed:
    // C2S region (dead SB tail) has no readers since the stage-4 sync.
#pragma unroll
    for (int nt = 0; nt < 2; nt++) {
      const f32x4 accv = nt ? acc1 : acc0;
      const int oc = nt * 16 + (lane & 15);
      const float bv = b2[oc];
#pragma unroll
      for (int r = 0; r < 4; r++) {
        const int px = wid * 16 + kg * 4 + r;     // C row = (lane>>4)*4 + reg
        if (px < 49) {
          const int y = px / 7, xx = px - y * 7;
          S[C2S + oc * 56 + y * 8 + xx] = lrelu(accv[r] + bv);
        }
      }
    }
  }
  __syncthreads();

  // ---- stage 6: conv3 32->8 3x3, K split in 8 groups of 4 ic, pw3 f4 loads ----
  {
    const int px = t & 31, ic8 = t >> 5;
    if (px < 25) {
      const int y = px / 5, xx = px - y * 5;
      float p[8] = {0,0,0,0,0,0,0,0};
      const float4* pw34 = (const float4*)pw3;
#pragma unroll
      for (int i = 0; i < 4; i++) {
        const int icg = ic8 * 4 + i;
        float rr[9];
#pragma unroll
        for (int ky = 0; ky < 3; ky++) {
          const int base = C2S + icg * 56 + (y + ky) * 8 + xx;
          rr[ky * 3 + 0] = S[base];
          rr[ky * 3 + 1] = S[base + 1];
          rr[ky * 3 + 2] = S[base + 2];
        }
#pragma unroll
        for (int oc = 0; oc < 8; oc++) {
          const float4 f0 = pw34[(icg * 8 + oc) * 3 + 0];
          const float4 f1 = pw34[(icg * 8 + oc) * 3 + 1];
          const float4 f2 = pw34[(icg * 8 + oc) * 3 + 2];
          p[oc] = fmaf(rr[0], f0.x, fmaf(rr[1], f0.y, fmaf(rr[2], f0.z,
                  fmaf(rr[3], f0.w, fmaf(rr[4], f1.x, fmaf(rr[5], f1.y,
                  fmaf(rr[6], f1.z, fmaf(rr[7], f1.w, fmaf(rr[8], f2.x, p[oc])))))))));
        }
      }
      float* wpp = &S[P6 + px * 64 + ic8 * 8];
#pragma unroll
      for (int oc = 0; oc < 8; oc++) wpp[oc] = p[oc];
    }
  }
  __syncthreads();
  if (t < 200) {
    const int oc = t & 7, px = t >> 3;
    float s = b3[oc];
    const float* rp = &S[P6 + px * 64 + oc];
#pragma unroll
    for (int g = 0; g < 8; g++) s += rp[g * 8];
    S[C3S + oc * 25 + px] = lrelu(s);
  }
  __syncthreads();

  // ---- stage 7: dense 200->64 partials, 4 chunks (56/56/56/32), float4 ----
  {
    const int o = t & 63, chunk = t >> 6;
    const int start = chunk * 56;
    const int cnt = (chunk == 3) ? 8 : 14;
    const float4* wr4 = (const float4*)&dw1[o * 200 + start];
    const float4* cr4 = (const float4*)&S[C3S + start];
    float acc = 0.f;
    for (int i = 0; i < cnt; i++) {   // runtime bound OK: memory only
      const float4 wv = wr4[i], cv = cr4[i];
      acc += wv.x * cv.x + wv.y * cv.y + wv.z * cv.z + wv.w * cv.w;
    }
    S[D1P + chunk * 64 + o] = acc;
  }
  __syncthreads();

  // ---- dense head: wave 0 only, no workgroup barriers (waves 1-3 retire) ----
  if (t < 64) {
    S[D1 + t] = lrelu(S[D1P + t] + S[D1P + 64 + t] + S[D1P + 128 + t] +
                      S[D1P + 192 + t] + db1[t]);
    __builtin_amdgcn_s_waitcnt(0); __builtin_amdgcn_wave_barrier();
    if (t < 32) {
      float acc = db2[t];
      const float4* wr = (const float4*)&dw2[t * 64];
      const float4* dr = (const float4*)&S[D1];
#pragma unroll
      for (int i = 0; i < 16; i++) acc = fma4(wr[i], dr[i], acc);
      S[D2 + t] = lrelu(acc);
    }
    __builtin_amdgcn_s_waitcnt(0); __builtin_amdgcn_wave_barrier();
    if (t < 16) {
      float acc = db3[t];
      const float4* wr = (const float4*)&dw3[t * 32];
      const float4* dr = (const float4*)&S[D2];
#pragma unroll
      for (int i = 0; i < 8; i++) acc = fma4(wr[i], dr[i], acc);
      S[D3 + t] = lrelu(acc);
    }
    __builtin_amdgcn_s_waitcnt(0); __builtin_amdgcn_wave_barrier();
    if (t < 8) {
      float acc = db4[t];
      const float4* wr = (const float4*)&dw4[t * 16];
      const float4* dr = (const float4*)&S[D3];
#pragma unroll
      for (int i = 0; i < 4; i++) acc = fma4(wr[i], dr[i], acc);
      S[D4 + t] = lrelu(acc);
    }
    __builtin_amdgcn_s_waitcnt(0); __builtin_amdgcn_wave_barrier();
    if (t < 2) {
      float acc = db5[t];
      const float4* wr = (const float4*)&dw5[t * 8];
      const float4* dr = (const float4*)&S[D4];
#pragma unroll
      for (int i = 0; i < 2; i++) acc = fma4(wr[i], dr[i], acc);
      out[(size_t)b * 2 + t] = acc;
    }
  }
}

extern "C" void kernel_launch(void* const* d_in, const int* in_sizes, int n_in,
                              void* d_out, int out_size, void* d_ws, size_t ws_size,
                              hipStream_t stream) {
  const float* x   = (const float*)d_in[0];
  const float* w1  = (const float*)d_in[1];
  const float* b1  = (const float*)d_in[2];
  const float* wt  = (const float*)d_in[3];
  const float* bt  = (const float*)d_in[4];
  const float* wp  = (const float*)d_in[5];
  const float* bp  = (const float*)d_in[6];
  const float* wg  = (const float*)d_in[7];
  const float* bg  = (const float*)d_in[8];
  const float* wo  = (const float*)d_in[9];
  const float* bo  = (const float*)d_in[10];
  const float* w2  = (const float*)d_in[11];
  const float* b2  = (const float*)d_in[12];
  const float* w3  = (const float*)d_in[13];
  const float* b3  = (const float*)d_in[14];
  const float* dw1 = (const float*)d_in[15];
  const float* db1 = (const float*)d_in[16];
  const float* dw2 = (const float*)d_in[17];
  const float* db2 = (const float*)d_in[18];
  const float* dw3 = (const float*)d_in[19];
  const float* db3 = (const float*)d_in[20];
  const float* dw4 = (const float*)d_in[21];
  const float* db4 = (const float*)d_in[22];
  const float* dw5 = (const float*)d_in[23];
  const float* db5 = (const float*)d_in[24];

  float* pw = (float*)d_ws;             // wb2: 9216 dw (bf16x2), pw3: 3072 dw
  repack_w23<<<32, 256, 0, stream>>>(w2, w3, pw);
  const u16* wb2 = (const u16*)pw;
  const float* pw3 = pw + 9216;

  int B = in_sizes[0] / 121;
  braggnn_fused<<<B, 256, 0, stream>>>(
      x, w1, b1, wt, bt, wp, bp, wg, bg, wo, bo, wb2, pw3, b2, b3,
      dw1, db1, dw2, db2, dw3, db3, dw4, db4, dw5, db5,
      (float*)d_out);
}

// Round 4
// 1058.136 us; speedup vs baseline: 1.0357x; 1.0152x over previous
//
#include <hip/hip_runtime.h>

#define NEG 0.01f
__device__ __forceinline__ float lrelu(float v){ return v >= 0.f ? v : NEG * v; }

typedef float v2f __attribute__((ext_vector_type(2)));
typedef short bf16x8 __attribute__((ext_vector_type(8)));   // 8 bf16 = 4 VGPRs
typedef float f32x4 __attribute__((ext_vector_type(4)));
typedef unsigned short u16;

__device__ __forceinline__ u16 f2bf(float f) {   // RNE f32 -> bf16 (finite inputs)
  unsigned u = __float_as_uint(f);
  return (u16)((u + 0x7FFFu + ((u >> 16) & 1u)) >> 16);
}
__device__ __forceinline__ float bflo(unsigned u){ return __uint_as_float(u << 16); }
__device__ __forceinline__ float bfhi(unsigned u){ return __uint_as_float(u & 0xffff0000u); }
__device__ __forceinline__ float bfu(u16 v){ return __uint_as_float((unsigned)v << 16); }

__device__ __forceinline__ float fma4(float4 wv, float4 hv, float acc) {
  return fmaf(wv.x, hv.x, fmaf(wv.y, hv.y, fmaf(wv.z, hv.z, fmaf(wv.w, hv.w, acc))));
}

// ---- LDS plan: TWO per-patch arenas of 6156 dw each; S[12312] = 49248 B ----
// Per-patch offsets (dw, add base = p*6156):
// Phase A (0-4a): XS@0(121, dies st-1) | G@0 bf16 [81][32] (648 dw, born 2a over
//                 dead XS, dies after 2c) | H2B@648 bf16 [81px][64ic] (2592 dw,
//                 dies at st-4 internal bar) | SB@3240 fp32 [81][36] (2916 dw,
//                 dies after st-4 reads). Peak 6156.
// Phase B (4b-5): H4@0 bf16 [81][72] rows stride 36 dw (3240 dw = exactly G+H2B
//                 region); st-5 MFMA from H4 + global wb2; epilogue writes
//                 C2S@3240 (1792, over dead SB head). st-5 A-reads for m>=49
//                 reach dw base+3652 (in-arena; possibly NaN-as-bf16 garbage;
//                 those MFMA C-rows are discarded — rows independent).
// Phase C (6+):   P6@0(1600) C3S@1600 D1P@1800 D1@2056 D2@2120 D3@2152 D4@2168
// RULES:
//  (R2)  no runtime-bound loop may index a register array — full unroll +
//        per-iteration predicate only (violation = 810 MB scratch traffic).
//  (R9)  dense head in wave 0 only (s_waitcnt+wave_barrier ordering).
//  (R13) stage-2a packs theta+phi via v2f fma (v_pk_fma_f32).
//  (R14) stage-5 = bf16 MFMA 16x16x32. A: m=l&15, k=8*(l>>4)+i; B from global
//        wb2 [tap][oc][ic]; C/D row=(l>>4)*4+reg, col=l&15. Rows m>=49 discarded.
//  (R15) H2 lives as bf16 from birth (stage-1 RNE pack); residual rounds ONCE.
//  (R18) TWO patches per block, stage bodies in runtime p-loops (unroll 1),
//        barriers OUTSIDE the loops: r0-r3 showed dur pinned at ~1120us with
//        occupancy 10.7-14.2 waves and VALU work varying 1.75x -> per-block
//        latency envelope (~46us: barrier drains + per-stage L2 weight-load
//        chains) is the limiter. 2 patches/block halves barriers per patch
//        (12->6) and makes pass-2 weights L1-warm. gReg carry (old R8) retired:
//        G stashed to LDS bf16 to keep VGPR flat across p-loop.
#define ARENA 6156
#define XS   0
#define G0   0
#define H2B  648
#define SB   3240
#define H4   0
#define C2S  3240
#define P6   0
#define C3S  1600
#define D1P  1800
#define D1   2056
#define D2   2120
#define D3   2152
#define D4   2168

// repack: w2 [oc32][ic64][9] -> wb2 bf16 [tap9][oc32][ic64] (18432 u16 = 9216 dw)
//         w3 [oc8][ic32][9]  -> pw3 fp32 [ic32][oc8][12] (pad3) at dw offset 9216
__global__ void repack_w23(const float* __restrict__ w2, const float* __restrict__ w3,
                           float* __restrict__ pw) {
  int idx = blockIdx.x * 256 + threadIdx.x;
  u16* wb2 = (u16*)pw;
  for (int i = idx; i < 9 * 32 * 64 + 32 * 8 * 12; i += gridDim.x * 256) {
    if (i < 9 * 32 * 64) {
      int ic = i & 63, oc = (i >> 6) & 31, tap = i >> 11;
      wb2[i] = f2bf(w2[(oc * 64 + ic) * 9 + tap]);
    } else {
      int j = i - 9 * 32 * 64;
      int s = j % 12, rest = j / 12, oc = rest & 7, ic = rest >> 3;
      pw[9216 + j] = (s < 9) ? w3[(oc * 32 + ic) * 9 + s] : 0.f;
    }
  }
}

__global__ __launch_bounds__(256, 3) void braggnn_fused(
    const float* __restrict__ x,
    const float* __restrict__ w1, const float* __restrict__ b1,
    const float* __restrict__ wt, const float* __restrict__ bt,
    const float* __restrict__ wp, const float* __restrict__ bp,
    const float* __restrict__ wg, const float* __restrict__ bg,
    const float* __restrict__ wo, const float* __restrict__ bo,
    const u16* __restrict__ wb2, const float* __restrict__ pw3,
    const float* __restrict__ b2,
    const float* __restrict__ b3,
    const float* __restrict__ dw1, const float* __restrict__ db1,
    const float* __restrict__ dw2, const float* __restrict__ db2,
    const float* __restrict__ dw3, const float* __restrict__ db3,
    const float* __restrict__ dw4, const float* __restrict__ db4,
    const float* __restrict__ dw5, const float* __restrict__ db5,
    float* __restrict__ out, int nP)
{
  const int b = blockIdx.x;
  const int t = threadIdx.x;
  const int p0 = 2 * b;
  const int p1 = (2 * b + 1 < nP) ? 2 * b + 1 : nP - 1;

  __shared__ __align__(16) float S[2 * ARENA];   // 49248 B

  // ---- stage 0: load both 11x11 patches (waves 0 and 2) ----
  if (t < 121) S[XS + t] = x[(size_t)p0 * 121 + t];
  else if (t >= 128 && t < 249) S[ARENA + XS + (t - 128)] = x[(size_t)p1 * 121 + (t - 128)];
  __syncthreads();

  // ---- stage 1: conv1 1->64 3x3, oc-PAIRED -> H2B bf16 [px][64] (R15) ----
  {
    const int ocp = t & 31, pg = t >> 5;       // oc = 2*ocp, 2*ocp+1; pg 0..7
    float wreg[18];                            // loaded ONCE, reused both patches
#pragma unroll
    for (int i = 0; i < 18; i++) wreg[i] = w1[ocp * 18 + i];
    const float bv0 = b1[2 * ocp], bv1 = b1[2 * ocp + 1];
#pragma unroll 1
    for (int p = 0; p < 2; p++) {
      const int base = p * ARENA;
      for (int px = pg; px < 81; px += 8) {
        const int y = px / 9, xx = px - y * 9;
        const float* xr = &S[base + XS + y * 11 + xx];
        float a0 = bv0, a1 = bv1;
#pragma unroll
        for (int ky = 0; ky < 3; ky++)
#pragma unroll
          for (int kx = 0; kx < 3; kx++) {
            const float v = xr[ky * 11 + kx];
            a0 = fmaf(v, wreg[ky * 3 + kx], a0);
            a1 = fmaf(v, wreg[9 + ky * 3 + kx], a1);
          }
        ((unsigned*)S)[base + H2B + px * 32 + ocp] =
            (unsigned)f2bf(a0) | ((unsigned)f2bf(a1) << 16);
      }
      __syncthreads();   // p0: XS1 still needed by p1 loop? arenas disjoint; this
                         // barrier (inside loop) orders H2B_p for stage 2a AND is
                         // harmless for p1 (uniform trip count).
    }
  }

  // ---- stage 2 pass A (R13): fused theta/phi packed + g -> SB + G stash ----
#pragma unroll 1
  for (int p = 0; p < 2; p++) {
    const int base = p * ARENA;
    const int oc = t & 31, pxb = t >> 5;
    const float4* wt4 = (const float4*)wt;
    const float4* wp4 = (const float4*)wp;
    const float4* wg4 = (const float4*)wg;
    const unsigned* H2u = (const unsigned*)S + base + H2B;
    u16* Gp = (u16*)&S[base + G0];
    v2f aTP[10];
#pragma unroll
    for (int i = 0; i < 10; i++) aTP[i] = (v2f){0.f, 0.f};
    float aG[10] = {0,0,0,0,0,0,0,0,0,0};
#pragma unroll 1
    for (int k8 = 0; k8 < 8; k8++) {
      const float4 wT0 = wt4[oc * 16 + 2 * k8];
      const float4 wP0 = wp4[oc * 16 + 2 * k8];
      const v2f q0 = {wT0.x, wP0.x}, q1 = {wT0.y, wP0.y};
      const v2f q2 = {wT0.z, wP0.z}, q3 = {wT0.w, wP0.w};
      const float4 wT1 = wt4[oc * 16 + 2 * k8 + 1];
      const float4 wP1 = wp4[oc * 16 + 2 * k8 + 1];
      const v2f q4 = {wT1.x, wP1.x}, q5 = {wT1.y, wP1.y};
      const v2f q6 = {wT1.z, wP1.z}, q7 = {wT1.w, wP1.w};
      const float4 wG0 = wg4[oc * 16 + 2 * k8];
      const float4 wG1 = wg4[oc * 16 + 2 * k8 + 1];
#pragma unroll
      for (int i = 0; i < 10; i++) {
        const uint4 hv = *(const uint4*)&H2u[(pxb + 8 * i) * 32 + k8 * 4];
        const float h0 = bflo(hv.x), h1 = bfhi(hv.x);
        const float h2 = bflo(hv.y), h3 = bfhi(hv.y);
        const float h4 = bflo(hv.z), h5 = bfhi(hv.z);
        const float h6 = bflo(hv.w), h7 = bfhi(hv.w);
        aTP[i] = __builtin_elementwise_fma(q0, (v2f){h0, h0}, aTP[i]);
        aTP[i] = __builtin_elementwise_fma(q1, (v2f){h1, h1}, aTP[i]);
        aTP[i] = __builtin_elementwise_fma(q2, (v2f){h2, h2}, aTP[i]);
        aTP[i] = __builtin_elementwise_fma(q3, (v2f){h3, h3}, aTP[i]);
        aTP[i] = __builtin_elementwise_fma(q4, (v2f){h4, h4}, aTP[i]);
        aTP[i] = __builtin_elementwise_fma(q5, (v2f){h5, h5}, aTP[i]);
        aTP[i] = __builtin_elementwise_fma(q6, (v2f){h6, h6}, aTP[i]);
        aTP[i] = __builtin_elementwise_fma(q7, (v2f){h7, h7}, aTP[i]);
        aG[i] = fmaf(h0, wG0.x, fmaf(h1, wG0.y, fmaf(h2, wG0.z, fmaf(h3, wG0.w,
                fmaf(h4, wG1.x, fmaf(h5, wG1.y, fmaf(h6, wG1.z,
                fmaf(h7, wG1.w, aG[i]))))))));
      }
    }
    const float bT = bt[oc], bP = bp[oc], bG = bg[oc];
#pragma unroll
    for (int i = 0; i < 10; i++) {
      const int px = pxb + 8 * i;
      S[base + SB + px * 36 + oc] = (aTP[i].x + bT) * (aTP[i].y + bP);
      Gp[px * 32 + oc] = f2bf(aG[i] + bG);
    }
    if (t < 32) {          // px = 80 leftover: oc = t
      float aT8 = 0.f, aP8 = 0.f, aG8 = 0.f;
#pragma unroll 1
      for (int k8 = 0; k8 < 8; k8++) {
        const uint4 hv = *(const uint4*)&H2u[80 * 32 + k8 * 4];
        const float h0 = bflo(hv.x), h1 = bfhi(hv.x);
        const float h2 = bflo(hv.y), h3 = bfhi(hv.y);
        const float h4 = bflo(hv.z), h5 = bfhi(hv.z);
        const float h6 = bflo(hv.w), h7 = bfhi(hv.w);
        const float4 a = wt4[t * 16 + 2 * k8], a2 = wt4[t * 16 + 2 * k8 + 1];
        const float4 c = wp4[t * 16 + 2 * k8], c2 = wp4[t * 16 + 2 * k8 + 1];
        const float4 e = wg4[t * 16 + 2 * k8], e2 = wg4[t * 16 + 2 * k8 + 1];
        aT8 = fmaf(h0,a.x,fmaf(h1,a.y,fmaf(h2,a.z,fmaf(h3,a.w,
              fmaf(h4,a2.x,fmaf(h5,a2.y,fmaf(h6,a2.z,fmaf(h7,a2.w,aT8))))))));
        aP8 = fmaf(h0,c.x,fmaf(h1,c.y,fmaf(h2,c.z,fmaf(h3,c.w,
              fmaf(h4,c2.x,fmaf(h5,c2.y,fmaf(h6,c2.z,fmaf(h7,c2.w,aP8))))))));
        aG8 = fmaf(h0,e.x,fmaf(h1,e.y,fmaf(h2,e.z,fmaf(h3,e.w,
              fmaf(h4,e2.x,fmaf(h5,e2.y,fmaf(h6,e2.z,fmaf(h7,e2.w,aG8))))))));
      }
      S[base + SB + 80 * 36 + t] = (aT8 + bt[t]) * (aP8 + bp[t]);
      Gp[80 * 32 + t] = f2bf(aG8 + bg[t]);
    }
  }
  __syncthreads();

  // ---- stage 2 pass B: softmax over W (9) in place on SB ----
#pragma unroll 1
  for (int p = 0; p < 2; p++) {
    const int base = p * ARENA;
    auto sm = [&](int r) {
      const int oc = r & 31, y = r >> 5;
      const int bb = base + SB + y * 9 * 36 + oc;
      float v[9]; float m = -1e30f;
#pragma unroll
      for (int k = 0; k < 9; k++) { v[k] = S[bb + k * 36]; m = fmaxf(m, v[k]); }
      float s = 0.f;
#pragma unroll
      for (int k = 0; k < 9; k++) { v[k] = __expf(v[k] - m); s += v[k]; }
      const float inv = 1.f / s;
#pragma unroll
      for (int k = 0; k < 9; k++) S[bb + k * 36] = v[k] * inv;
    };
    sm(t);
    if (t < 32) sm(256 + t);
  }
  __syncthreads();

  // ---- stage 2 pass C: SB = attn * G (G from LDS stash, in place) ----
#pragma unroll 1
  for (int p = 0; p < 2; p++) {
    const int base = p * ARENA;
    const int oc = t & 31, pxb = t >> 5;
    const u16* Gp = (const u16*)&S[base + G0];
#pragma unroll
    for (int i = 0; i < 10; i++) {
      const int px = pxb + 8 * i;
      const int idx = base + SB + px * 36 + oc;
      S[idx] = bfu(Gp[px * 32 + oc]) * S[idx];
    }
    if (t < 32) {
      const int idx = base + SB + 80 * 36 + t;
      S[idx] = bfu(Gp[80 * 32 + t]) * S[idx];
    }
  }
  __syncthreads();

  // ---- stage 4: wo 1x1 (32->64) + residual + lrelu -> H4 bf16 [px][72] ----
#pragma unroll 1
  for (int p = 0; p < 2; p++) {
    const int base = p * ARENA;
    const int ocq = t >> 4, q = t & 15;
    const int oc0 = ocq * 4;
    int pxs[6];
#pragma unroll
    for (int j = 0; j < 6; j++) { int pp = q + 16 * j; pxs[j] = (pp > 80) ? 80 : pp; }
    float a0[6] = {0,0,0,0,0,0}, a1[6] = {0,0,0,0,0,0};
    float a2[6] = {0,0,0,0,0,0}, a3[6] = {0,0,0,0,0,0};
    const float4* wo4 = (const float4*)wo;
#pragma unroll 2
    for (int k4 = 0; k4 < 8; k4++) {
      const float4 u0 = wo4[(oc0 + 0) * 8 + k4];
      const float4 u1 = wo4[(oc0 + 1) * 8 + k4];
      const float4 u2 = wo4[(oc0 + 2) * 8 + k4];
      const float4 u3 = wo4[(oc0 + 3) * 8 + k4];
#pragma unroll
      for (int j = 0; j < 6; j++) {
        const float4 gv = *(const float4*)&S[base + SB + pxs[j] * 36 + k4 * 4];
        a0[j] = fma4(u0, gv, a0[j]); a1[j] = fma4(u1, gv, a1[j]);
        a2[j] = fma4(u2, gv, a2[j]); a3[j] = fma4(u3, gv, a3[j]);
      }
    }
    // (R17) fold residual into accumulators BEFORE the barrier.
    {
      const unsigned* H2u = (const unsigned*)S + base + H2B;
#pragma unroll
      for (int j = 0; j < 6; j++) {
        const uint2 h = *(const uint2*)&H2u[pxs[j] * 32 + (oc0 >> 1)];
        a0[j] += bflo(h.x); a1[j] += bfhi(h.x);
        a2[j] += bflo(h.y); a3[j] += bfhi(h.y);
      }
    }
    __syncthreads();   // arena-p reads done; H4_p writes below clobber G_p+H2B_p
    const float bo0 = bo[oc0], bo1 = bo[oc0 + 1], bo2 = bo[oc0 + 2], bo3 = bo[oc0 + 3];
#pragma unroll
    for (int j = 0; j < 6; j++) {
      if (q + 16 * j <= 80) {   // unique-write predicate, compile-time unrolled
        const int px = pxs[j];
        const float v0 = lrelu(a0[j] + bo0);
        const float v1 = lrelu(a1[j] + bo1);
        const float v2 = lrelu(a2[j] + bo2);
        const float v3 = lrelu(a3[j] + bo3);
        uint2 pk;
        pk.x = (unsigned)f2bf(v0) | ((unsigned)f2bf(v1) << 16);
        pk.y = (unsigned)f2bf(v2) | ((unsigned)f2bf(v3) << 16);
        *(uint2*)&((unsigned*)S)[base + H4 + px * 36 + (oc0 >> 1)] = pk;
      }
    }
  }
  __syncthreads();

  // ---- stage 5 (R14): conv2 64->32 3x3 as bf16 MFMA 16x16x32 ----
#pragma unroll 1
  for (int p = 0; p < 2; p++) {
    const int base = p * ARENA;
    const int lane = t & 63, wid = t >> 6;
    const int m = lane & 15, kg = lane >> 4;      // A row, k-group
    const int opx = wid * 16 + m;                 // output px this lane feeds
    const int oy = opx / 7, ox = opx - oy * 7;
    const char* Sb = (const char*)S;
    int aoff = base * 4 + (oy * 9 + ox) * 144 + kg * 16;  // bytes (144 B/row)
    const u16* wbl = wb2 + (lane & 15) * 64 + kg * 8;
    f32x4 acc0 = {0.f, 0.f, 0.f, 0.f}, acc1 = {0.f, 0.f, 0.f, 0.f};
#pragma unroll 1
    for (int ky = 0; ky < 3; ky++) {
#pragma unroll
      for (int kx = 0; kx < 3; kx++) {
#pragma unroll
        for (int ks = 0; ks < 2; ks++) {
          const bf16x8 av = *(const bf16x8*)(Sb + (aoff + kx * 144 + ks * 64));
          const bf16x8 b0v = *(const bf16x8*)(wbl + kx * 2048 + ks * 32);
          const bf16x8 b1v = *(const bf16x8*)(wbl + kx * 2048 + ks * 32 + 1024);
          acc0 = __builtin_amdgcn_mfma_f32_16x16x32_bf16(av, b0v, acc0, 0, 0, 0);
          acc1 = __builtin_amdgcn_mfma_f32_16x16x32_bf16(av, b1v, acc1, 0, 0, 0);
        }
      }
      aoff += 9 * 144;        // next ky input row
      wbl  += 3 * 2048;       // next ky tap group
    }
    // epilogue: bias + lrelu -> C2S [32 oc][7 y][8 x] (fp32). C2S region (dead
    // SB head) disjoint from H4 -> no barrier vs other waves' A-reads.
#pragma unroll
    for (int nt = 0; nt < 2; nt++) {
      const f32x4 accv = nt ? acc1 : acc0;
      const int oc = nt * 16 + (lane & 15);
      const float bv = b2[oc];
#pragma unroll
      for (int r = 0; r < 4; r++) {
        const int px = wid * 16 + kg * 4 + r;     // C row = (lane>>4)*4 + reg
        if (px < 49) {
          const int y = px / 7, xx = px - y * 7;
          S[base + C2S + oc * 56 + y * 8 + xx] = lrelu(accv[r] + bv);
        }
      }
    }
  }
  __syncthreads();

  // ---- stage 6: conv3 32->8 3x3, K split in 8 groups of 4 ic ----
#pragma unroll 1
  for (int p = 0; p < 2; p++) {
    const int base = p * ARENA;
    const int px = t & 31, ic8 = t >> 5;
    if (px < 25) {
      const int y = px / 5, xx = px - y * 5;
      float pr[8] = {0,0,0,0,0,0,0,0};
      const float4* pw34 = (const float4*)pw3;
#pragma unroll
      for (int i = 0; i < 4; i++) {
        const int icg = ic8 * 4 + i;
        float rr[9];
#pragma unroll
        for (int ky = 0; ky < 3; ky++) {
          const int bb = base + C2S + icg * 56 + (y + ky) * 8 + xx;
          rr[ky * 3 + 0] = S[bb];
          rr[ky * 3 + 1] = S[bb + 1];
          rr[ky * 3 + 2] = S[bb + 2];
        }
#pragma unroll
        for (int oc = 0; oc < 8; oc++) {
          const float4 f0 = pw34[(icg * 8 + oc) * 3 + 0];
          const float4 f1 = pw34[(icg * 8 + oc) * 3 + 1];
          const float4 f2 = pw34[(icg * 8 + oc) * 3 + 2];
          pr[oc] = fmaf(rr[0], f0.x, fmaf(rr[1], f0.y, fmaf(rr[2], f0.z,
                   fmaf(rr[3], f0.w, fmaf(rr[4], f1.x, fmaf(rr[5], f1.y,
                   fmaf(rr[6], f1.z, fmaf(rr[7], f1.w, fmaf(rr[8], f2.x, pr[oc])))))))));
        }
      }
      float* wpp = &S[base + P6 + px * 64 + ic8 * 8];
#pragma unroll
      for (int oc = 0; oc < 8; oc++) wpp[oc] = pr[oc];
    }
  }
  __syncthreads();
#pragma unroll 1
  for (int p = 0; p < 2; p++) {
    const int base = p * ARENA;
    if (t < 200) {
      const int oc = t & 7, px = t >> 3;
      float s = b3[oc];
      const float* rp = &S[base + P6 + px * 64 + oc];
#pragma unroll
      for (int g = 0; g < 8; g++) s += rp[g * 8];
      S[base + C3S + oc * 25 + px] = lrelu(s);
    }
  }
  __syncthreads();

  // ---- stage 7: dense 200->64 partials, 4 chunks (56/56/56/32), float4 ----
#pragma unroll 1
  for (int p = 0; p < 2; p++) {
    const int base = p * ARENA;
    const int o = t & 63, chunk = t >> 6;
    const int start = chunk * 56;
    const int cnt = (chunk == 3) ? 8 : 14;
    const float4* wr4 = (const float4*)&dw1[o * 200 + start];
    const float4* cr4 = (const float4*)&S[base + C3S + start];
    float acc = 0.f;
    for (int i = 0; i < cnt; i++) {   // runtime bound OK: memory only
      const float4 wv = wr4[i], cv = cr4[i];
      acc += wv.x * cv.x + wv.y * cv.y + wv.z * cv.z + wv.w * cv.w;
    }
    S[base + D1P + chunk * 64 + o] = acc;
  }
  __syncthreads();

  // ---- dense head: wave 0 only, no workgroup barriers (waves 1-3 retire) ----
  if (t < 64) {
#pragma unroll 1
    for (int p = 0; p < 2; p++) {
      const int base = p * ARENA;
      const int pidx = p ? p1 : p0;
      S[base + D1 + t] = lrelu(S[base + D1P + t] + S[base + D1P + 64 + t] +
                               S[base + D1P + 128 + t] + S[base + D1P + 192 + t] +
                               db1[t]);
      __builtin_amdgcn_s_waitcnt(0); __builtin_amdgcn_wave_barrier();
      if (t < 32) {
        float acc = db2[t];
        const float4* wr = (const float4*)&dw2[t * 64];
        const float4* dr = (const float4*)&S[base + D1];
#pragma unroll
        for (int i = 0; i < 16; i++) acc = fma4(wr[i], dr[i], acc);
        S[base + D2 + t] = lrelu(acc);
      }
      __builtin_amdgcn_s_waitcnt(0); __builtin_amdgcn_wave_barrier();
      if (t < 16) {
        float acc = db3[t];
        const float4* wr = (const float4*)&dw3[t * 32];
        const float4* dr = (const float4*)&S[base + D2];
#pragma unroll
        for (int i = 0; i < 8; i++) acc = fma4(wr[i], dr[i], acc);
        S[base + D3 + t] = lrelu(acc);
      }
      __builtin_amdgcn_s_waitcnt(0); __builtin_amdgcn_wave_barrier();
      if (t < 8) {
        float acc = db4[t];
        const float4* wr = (const float4*)&dw4[t * 16];
        const float4* dr = (const float4*)&S[base + D3];
#pragma unroll
        for (int i = 0; i < 4; i++) acc = fma4(wr[i], dr[i], acc);
        S[base + D4 + t] = lrelu(acc);
      }
      __builtin_amdgcn_s_waitcnt(0); __builtin_amdgcn_wave_barrier();
      if (t < 2) {
        float acc = db5[t];
        const float4* wr = (const float4*)&dw5[t * 8];
        const float4* dr = (const float4*)&S[base + D4];
#pragma unroll
        for (int i = 0; i < 2; i++) acc = fma4(wr[i], dr[i], acc);
        out[(size_t)pidx * 2 + t] = acc;
      }
      __builtin_amdgcn_s_waitcnt(0); __builtin_amdgcn_wave_barrier();
    }
  }
}

extern "C" void kernel_launch(void* const* d_in, const int* in_sizes, int n_in,
                              void* d_out, int out_size, void* d_ws, size_t ws_size,
                              hipStream_t stream) {
  const float* x   = (const float*)d_in[0];
  const float* w1  = (const float*)d_in[1];
  const float* b1  = (const float*)d_in[2];
  const float* wt  = (const float*)d_in[3];
  const float* bt  = (const float*)d_in[4];
  const float* wp  = (const float*)d_in[5];
  const float* bp  = (const float*)d_in[6];
  const float* wg  = (const float*)d_in[7];
  const float* bg  = (const float*)d_in[8];
  const float* wo  = (const float*)d_in[9];
  const float* bo  = (const float*)d_in[10];
  const float* w2  = (const float*)d_in[11];
  const float* b2  = (const float*)d_in[12];
  const float* w3  = (const float*)d_in[13];
  const float* b3  = (const float*)d_in[14];
  const float* dw1 = (const float*)d_in[15];
  const float* db1 = (const float*)d_in[16];
  const float* dw2 = (const float*)d_in[17];
  const float* db2 = (const float*)d_in[18];
  const float* dw3 = (const float*)d_in[19];
  const float* db3 = (const float*)d_in[20];
  const float* dw4 = (const float*)d_in[21];
  const float* db4 = (const float*)d_in[22];
  const float* dw5 = (const float*)d_in[23];
  const float* db5 = (const float*)d_in[24];

  float* pw = (float*)d_ws;             // wb2: 9216 dw (bf16x2), pw3: 3072 dw
  repack_w23<<<32, 256, 0, stream>>>(w2, w3, pw);
  const u16* wb2 = (const u16*)pw;
  const float* pw3 = pw + 9216;

  int B = in_sizes[0] / 121;
  int grid = (B + 1) / 2;
  braggnn_fused<<<grid, 256, 0, stream>>>(
      x, w1, b1, wt, bt, wp, bp, wg, bg, wo, bo, wb2, pw3, b2, b3,
      dw1, db1, dw2, db2, dw3, db3, dw4, db4, dw5, db5,
      (float*)d_out, B);
}